// Round 11
// baseline (1029.579 us; speedup 1.0000x reference)
//
#include <hip/hip_runtime.h>
#include <hip/hip_bf16.h>
#include <hip/hip_fp16.h>

// Problem constants: B=16, C=256, N=2048, NUM_SA=4
static constexpr int Bn = 16;
static constexpr int Cc = 256;
static constexpr int Nn = 2048;
static constexpr int C4 = 64;
static constexpr float LOG2E = 1.4426950408889634f;

typedef _Float16 half_t;
typedef __attribute__((ext_vector_type(8))) _Float16 half8;
typedef __attribute__((ext_vector_type(4))) _Float16 half4;
typedef __attribute__((ext_vector_type(8))) short short8;
typedef __attribute__((ext_vector_type(4))) float float4v;

static constexpr long sNC = (long)Nn * Cc;   // 524288
static constexpr long sNQ = (long)Nn * C4;   // 131072

#define DEVI __device__ __forceinline__

DEVI float bf2f(unsigned short u) { return __uint_as_float(((unsigned)u) << 16); }
DEVI unsigned short f2bf(float f) {
    unsigned x = __float_as_uint(f);
    x += 0x7fffu + ((x >> 16) & 1u);   // RNE
    return (unsigned short)(x >> 16);
}

// async global->LDS, 16B per lane. LDS dest = wave-uniform base + lane*16.
DEVI void gload16(const void* g, void* l) {
    __builtin_amdgcn_global_load_lds(
        (const __attribute__((address_space(1))) unsigned int*)g,
        (__attribute__((address_space(3))) unsigned int*)l, 16, 0, 0);
}

enum { EPI_RAW = 0, EPI_H = 1, EPI_XV = 2 };

// Canonical MFMA GEMM: Y[j][i] = epi( sum_k A[i*K+k] * B[j*K+k] )
template<int MODE, int BM, int BN, int WI, int WJ, bool BF16OUT>
__global__ __launch_bounds__(WI * WJ * 64)
void mgemm(const half_t* __restrict__ A, long aB,
           const half_t* __restrict__ Bm, long bB,
           void* __restrict__ Yv, long yB, int ldy,
           const float* __restrict__ bias,
           const float* __restrict__ bng, const float* __restrict__ bnb,
           const float* __restrict__ bnm, const float* __restrict__ bnv,
           int K)
{
    constexpr int NW = WI * WJ;
    __shared__ __align__(16) half_t Als[2][BM][32];
    __shared__ __align__(16) half_t Bls[2][BN][32];

    const int tid  = threadIdx.x;
    const int w    = tid >> 6;
    const int lane = tid & 63;
    const int wi   = w % WI;
    const int wj   = w / WI;
    const int quad = lane >> 4, m16 = lane & 15;
    const int lr   = lane >> 2, lc = lane & 3;
    const int b    = blockIdx.z;
    const int j0   = blockIdx.x * BN;
    const int i0   = blockIdx.y * BM;

    const half_t* Ab = A + (size_t)b * aB;
    const half_t* Bb = Bm + (size_t)b * bB;

    float4v acc[4][4];
    #pragma unroll
    for (int i = 0; i < 4; ++i)
        #pragma unroll
        for (int j = 0; j < 4; ++j) acc[i][j] = (float4v)0.f;

    for (int k0 = 0; k0 < K; k0 += 64) {
        #pragma unroll
        for (int s = 0; s < 2; ++s) {
            const int kk = k0 + s * 32 + lc * 8;
            #pragma unroll
            for (int t = 0; t < BM / (16 * NW); ++t) {
                const int row = (t * NW + w) * 16;
                gload16(Ab + (size_t)(i0 + row + lr) * K + kk, &Als[s][row][0]);
            }
            #pragma unroll
            for (int t = 0; t < BN / (16 * NW); ++t) {
                const int row = (t * NW + w) * 16;
                gload16(Bb + (size_t)(j0 + row + lr) * K + kk, &Bls[s][row][0]);
            }
        }
        __syncthreads();
        #pragma unroll
        for (int s = 0; s < 2; ++s) {
            half8 af[4], bf[4];
            #pragma unroll
            for (int t = 0; t < 4; ++t)
                af[t] = *(const half8*)&Als[s][wi * 64 + t * 16 + m16][quad * 8];
            #pragma unroll
            for (int t = 0; t < 4; ++t)
                bf[t] = *(const half8*)&Bls[s][wj * 64 + t * 16 + m16][quad * 8];
            #pragma unroll
            for (int ti = 0; ti < 4; ++ti)
                #pragma unroll
                for (int tj = 0; tj < 4; ++tj)
                    acc[ti][tj] = __builtin_amdgcn_mfma_f32_16x16x32_f16(
                        af[ti], bf[tj], acc[ti][tj], 0, 0, 0);
        }
        __syncthreads();
    }

    #pragma unroll
    for (int ti = 0; ti < 4; ++ti) {
        const int il = i0 + wi * 64 + ti * 16 + quad * 4;
        #pragma unroll
        for (int tj = 0; tj < 4; ++tj) {
            const int jl = j0 + wj * 64 + tj * 16 + m16;
            float4v v = acc[ti][tj];
            if (MODE == EPI_RAW) {
                half4 o;
                #pragma unroll
                for (int r = 0; r < 4; ++r) o[r] = (half_t)v[r];
                *(half4*)((half_t*)Yv + (size_t)b * yB + (size_t)jl * ldy + il) = o;
            } else if (MODE == EPI_H) {
                half4 o;
                #pragma unroll
                for (int r = 0; r < 4; ++r) {
                    const float sc = bng[il + r] * rsqrtf(bnv[il + r] + 1e-3f);
                    const float sh = bnb[il + r] - bnm[il + r] * sc;
                    o[r] = (half_t)fmaxf(fmaf(v[r], sc, sh), 0.f);
                }
                *(half4*)((half_t*)Yv + (size_t)b * yB + (size_t)jl * ldy + il) = o;
            } else {   // EPI_XV
                const float bj = bias[jl];
                if (BF16OUT) {
                    ushort4 o;
                    o.x = f2bf(v[0] + bj); o.y = f2bf(v[1] + bj);
                    o.z = f2bf(v[2] + bj); o.w = f2bf(v[3] + bj);
                    *(ushort4*)((unsigned short*)Yv + (size_t)b * yB + (size_t)jl * ldy + il) = o;
                } else {
                    half4 o;
                    #pragma unroll
                    for (int r = 0; r < 4; ++r) o[r] = (half_t)(v[r] + bj);
                    *(half4*)((half_t*)Yv + (size_t)b * yB + (size_t)jl * ldy + il) = o;
                }
            }
        }
    }
}

// Pass 1: E = q q^T tile stats (no E store) -> Pbuf[b][m][16 iblk][2].
// PROVEN round-7 version: (16,16,Bn) grid, massively parallel -- the
// round-10 strip version regressed 2-3x (1/16th the parallelism, serial
// online-merge chain).
__global__ __launch_bounds__(256)
void estats(const half_t* __restrict__ q, float* __restrict__ Pbuf)
{
    __shared__ __align__(16) half_t sA[128 * 64];
    __shared__ __align__(16) half_t sB[128 * 64];
    __shared__ float red[2][2][4][16][2];
    const int tid = threadIdx.x, w = tid >> 6, lane = tid & 63;
    const int wi = w & 1, wj = w >> 1, quad = lane >> 4, m16 = lane & 15;
    const int b = blockIdx.z, j0 = blockIdx.x * 128, i0 = blockIdx.y * 128;
    const half_t* qb = q + (size_t)b * sNQ;

    #pragma unroll
    for (int t = 0; t < 4; ++t) {
        const int g = w * 256 + t * 64 + lane;
        const int r = g >> 3, c = g & 7;
        const int cs = c ^ (r & 7);
        gload16(qb + (size_t)(i0 + r) * 64 + cs * 8, sA + (w * 256 + t * 64) * 8);
        gload16(qb + (size_t)(j0 + r) * 64 + cs * 8, sB + (w * 256 + t * 64) * 8);
    }
    __syncthreads();

    half8 an[4][2], bm[4][2];
    #pragma unroll
    for (int t = 0; t < 4; ++t)
        #pragma unroll
        for (int ks = 0; ks < 2; ++ks) {
            const int pc = ((ks * 4 + quad) ^ (m16 & 7)) * 8;
            an[t][ks] = *(const half8*)&sA[(wi * 64 + t * 16 + m16) * 64 + pc];
            bm[t][ks] = *(const half8*)&sB[(wj * 64 + t * 16 + m16) * 64 + pc];
        }

    #pragma unroll
    for (int tj = 0; tj < 4; ++tj) {
        float4v e[4];
        #pragma unroll
        for (int ti = 0; ti < 4; ++ti) {
            e[ti] = (float4v)0.f;
            e[ti] = __builtin_amdgcn_mfma_f32_16x16x32_f16(an[ti][0], bm[tj][0], e[ti], 0, 0, 0);
            e[ti] = __builtin_amdgcn_mfma_f32_16x16x32_f16(an[ti][1], bm[tj][1], e[ti], 0, 0, 0);
        }
        float lmax = -1e30f;
        #pragma unroll
        for (int ti = 0; ti < 4; ++ti)
            #pragma unroll
            for (int r = 0; r < 4; ++r) lmax = fmaxf(lmax, e[ti][r]);
        lmax = fmaxf(lmax, __shfl_xor(lmax, 16));
        lmax = fmaxf(lmax, __shfl_xor(lmax, 32));
        float ls = 0.f;
        #pragma unroll
        for (int ti = 0; ti < 4; ++ti)
            #pragma unroll
            for (int r = 0; r < 4; ++r) ls += __expf(e[ti][r] - lmax);
        ls += __shfl_xor(ls, 16);
        ls += __shfl_xor(ls, 32);
        if (quad == 0) { red[wi][wj][tj][m16][0] = lmax; red[wi][wj][tj][m16][1] = ls; }
    }
    __syncthreads();
    if (tid < 128) {
        const int wj2 = tid >> 6, tj2 = (tid >> 4) & 3, mm = tid & 15;
        const float m0 = red[0][wj2][tj2][mm][0], s0 = red[0][wj2][tj2][mm][1];
        const float m1 = red[1][wj2][tj2][mm][0], s1 = red[1][wj2][tj2][mm][1];
        const float M = fmaxf(m0, m1);
        const float S = s0 * __expf(m0 - M) + s1 * __expf(m1 - M);
        const int m = j0 + wj2 * 64 + tj2 * 16 + mm;
        *(float2*)(Pbuf + (((size_t)b * Nn + m) * 16 + blockIdx.y) * 2) = make_float2(M, S);
    }
}

// Merge 16 per-block partials -> off[b][m] = m*log2e + log2(S)
__global__ __launch_bounds__(256)
void statsreduce(const float* __restrict__ Pbuf, float* __restrict__ off)
{
    const int id = blockIdx.x * 256 + threadIdx.x;   // 0..32767
    const int b = id >> 11, m = id & 2047;
    const float2* p = (const float2*)(Pbuf + ((size_t)b * Nn + m) * 32);
    float M = -1e30f;
    #pragma unroll
    for (int i = 0; i < 16; ++i) M = fmaxf(M, p[i].x);
    float S = 0.f;
    #pragma unroll
    for (int i = 0; i < 16; ++i) S += p[i].y * __expf(p[i].x - M);
    off[(size_t)b * Nn + m] = fmaf(M, LOG2E, __log2f(S));
}

// Pass 2: fused attention-apply + t-GEMM + epilogue.
// 512 threads (8 waves), 1 block per (b, m-64-tile) -> 512 blocks.
// LDS 48 KB (sXV 32 + sP 8 + sOff 8) -> 2 co-resident blocks/CU.
// E A-fragments now live in a REGISTER double-buffer (anA/anB, named to
// avoid scratch): plain global loads issued at the chunk top alongside the
// sXV stage, drained at the same barrier (no added exposed latency; q is
// XCD-L2-hot), consumed the following half-chunk. Removes the sQA LDS
// round-trip: -32 KB reads -8 KB writes per chunk/block (~23% LDS traffic).
__global__ __launch_bounds__(512)
void flashxr(const half_t* __restrict__ q, const half_t* __restrict__ xv,
             const half_t* __restrict__ h, const float* __restrict__ offp,
             const half_t* __restrict__ tw, const float* __restrict__ tb,
             const float* __restrict__ bng, const float* __restrict__ bnb,
             const float* __restrict__ bnm, const float* __restrict__ bnv,
             float* __restrict__ outL, half_t* __restrict__ hNext)
{
    __shared__ __align__(16) half_t sXV[256 * 64];    // 32 KB; reused as sD[64][256]
    __shared__ __align__(16) half_t sP[64 * 64];      // 8 KB: P tile / cs buf
    __shared__ float sOff[Nn];                        // 8 KB

    const int tid = threadIdx.x, w = tid >> 6, lane = tid & 63;
    const int quad = lane >> 4, m16 = lane & 15;
    const int wiE = w & 1, wjE = w >> 1;        // E: n-32-half, m-16-tile (4)
    const int wi = w & 3, wj = w >> 2;          // XR: c-64-tile (4), m-32-tile (2)
    const int wjT = w;                          // T: co-32-tile (8)
    const int f = blockIdx.x;
    const int W = (f & 7) * 64 + (f >> 3);      // bijective over [0,512)
    const int b = W >> 5, j0 = (W & 31) * 64;
    const half_t* qb  = q + (size_t)b * sNQ;
    const half_t* xvb = xv + (size_t)b * sNC;   // [256][2048] half bits

    // E A-fragment register loads for chunk nc_ (plain global; L2-hot)
    #define LOAD_AN(dst, nc_)                                                   \
    {                                                                           \
        _Pragma("unroll")                                                       \
        for (int ti = 0; ti < 2; ++ti)                                          \
            _Pragma("unroll")                                                   \
            for (int s = 0; s < 2; ++s)                                         \
                dst[ti][s] = *(const half8*)(qb                                 \
                    + (size_t)((nc_) * 64 + wiE * 32 + ti * 16 + m16) * 64      \
                    + (s * 4 + quad) * 8);                                      \
    }

    #define STAGE_XV(nc_)                                                       \
    {                                                                           \
        _Pragma("unroll")                                                       \
        for (int t = 0; t < 4; ++t) {                                           \
            const int g = t * 512 + tid;                                        \
            const int r = g >> 3, c = g & 7;                                    \
            gload16(xvb + (size_t)r * Nn + (nc_) * 64 + ((c ^ (r & 7)) * 8),    \
                    sXV + (size_t)g * 8);                                       \
        }                                                                       \
    }

    // ---- prologue: stage sOff (8 KB); bq regs; anA for chunk 0 ----
    gload16(offp + (size_t)b * Nn + (size_t)tid * 4, sOff + (size_t)tid * 4);

    half8 bq[2];
    #pragma unroll
    for (int s = 0; s < 2; ++s)
        bq[s] = *(const half8*)(qb + (size_t)(j0 + wjE * 16 + m16) * 64 + (s * 4 + quad) * 8);

    half8 anA[2][2], anB[2][2];
    LOAD_AN(anA, 0);

    __syncthreads();   // drains sOff stage (+ anA/bq loads)

    float4v acc[4][2];
    #pragma unroll
    for (int i = 0; i < 4; ++i)
        #pragma unroll
        for (int j = 0; j < 2; ++j) acc[i][j] = (float4v)0.f;
    float csa = 0.f;
    const int mrow = wjE * 16 + m16;

    #define EPHASE(nc_, an)                                                     \
    {                                                                           \
        const int nbase = (nc_) * 64 + wiE * 32 + quad * 4;                     \
        _Pragma("unroll")                                                       \
        for (int ti = 0; ti < 2; ++ti) {                                        \
            float4v e = (float4v)0.f;                                           \
            e = __builtin_amdgcn_mfma_f32_16x16x32_f16(an[ti][0], bq[0], e, 0, 0, 0); \
            e = __builtin_amdgcn_mfma_f32_16x16x32_f16(an[ti][1], bq[1], e, 0, 0, 0); \
            const float4v o4 = *(const float4v*)&sOff[nbase + ti * 16];         \
            float c0 = 0.f; ushort4 pk;                                         \
            _Pragma("unroll")                                                   \
            for (int r = 0; r < 4; ++r) {                                       \
                const float p = __builtin_amdgcn_exp2f(fmaf(e[r], LOG2E, -o4[r])); \
                c0 += p; (&pk.x)[r] = f2bf(p);                                  \
            }                                                                   \
            csa += c0;                                                          \
            const int pc = (wiE * 4 + ti * 2 + (quad >> 1)) ^ (m16 & 7);        \
            *(ushort4*)&((unsigned short*)sP)[(size_t)mrow * 64 + pc * 8        \
                                              + (quad & 1) * 4] = pk;           \
        }                                                                       \
    }

    #define XRPHASE()                                                           \
    {                                                                           \
        _Pragma("unroll")                                                       \
        for (int ks = 0; ks < 2; ++ks) {                                        \
            short8 xa[4], pb[2];                                                \
            _Pragma("unroll")                                                   \
            for (int ti = 0; ti < 4; ++ti)                                      \
                xa[ti] = *(const short8*)&sXV[(size_t)(wi * 64 + ti * 16 + m16) * 64 \
                                              + (((ks * 4 + quad) ^ (m16 & 7)) * 8)]; \
            _Pragma("unroll")                                                   \
            for (int tj = 0; tj < 2; ++tj)                                      \
                pb[tj] = *(const short8*)&sP[(size_t)(wj * 32 + tj * 16 + m16) * 64 \
                                             + (((ks * 4 + quad) ^ (m16 & 7)) * 8)]; \
            __builtin_amdgcn_s_setprio(1);                                      \
            _Pragma("unroll")                                                   \
            for (int ti = 0; ti < 4; ++ti)                                      \
                _Pragma("unroll")                                               \
                for (int tj = 0; tj < 2; ++tj)                                  \
                    acc[ti][tj] = __builtin_amdgcn_mfma_f32_16x16x32_bf16(      \
                        xa[ti], pb[tj], acc[ti][tj], 0, 0, 0);                  \
            __builtin_amdgcn_s_setprio(0);                                      \
        }                                                                       \
    }

    for (int u = 0; u < 16; ++u) {
        const int ncE = 2 * u, ncO = 2 * u + 1;

        // ---- even sub-chunk: consume anA; prefetch anB (for odd) ----
        STAGE_XV(ncE);
        LOAD_AN(anB, ncO);
        __syncthreads();   // drains stage + anB loads (parallel L2 fetches)
        EPHASE(ncE, anA);
        __syncthreads();   // publishes sP
        XRPHASE();
        __syncthreads();   // XR reads done

        // ---- odd sub-chunk: consume anB; prefetch anA (for next even) ----
        STAGE_XV(ncO);
        if (u < 15) LOAD_AN(anA, ncE + 2);
        __syncthreads();
        EPHASE(ncO, anB);
        __syncthreads();
        XRPHASE();
        __syncthreads();
    }
    #undef LOAD_AN
    #undef STAGE_XV
    #undef EPHASE
    #undef XRPHASE

    // colsum reduce: quad butterfly, then cross-wiE via LDS (sP as floats)
    csa += __shfl_xor(csa, 16);
    csa += __shfl_xor(csa, 32);
    float* fb = (float*)sP;
    if (lane < 16) fb[wiE * 64 + wjE * 16 + lane] = csa;
    __syncthreads();
    float csr[2];
    #pragma unroll
    for (int tj = 0; tj < 2; ++tj) {
        const int m = wj * 32 + tj * 16 + m16;
        csr[tj] = 1.0f / (1e-9f + fb[m] + fb[64 + m]);
    }

    // d = h - xr*csr -> sD (fp16, swizzled [64 m][256 c], overlays sXV)
    const half_t* hb = h + (size_t)b * sNC;
    half_t* sD = sXV;
    #pragma unroll
    for (int ti = 0; ti < 4; ++ti) {
        const int cg = wi * 64 + ti * 16 + quad * 4;
        const int cc = (cg >> 3) ^ (m16 & 7);      // swizzled 16B chunk
        const int sub = (quad & 1) * 4;
        #pragma unroll
        for (int tj = 0; tj < 2; ++tj) {
            const int mr = wj * 32 + tj * 16 + m16;
            const int mg = j0 + mr;
            const half4 hv = *(const half4*)&hb[(size_t)mg * Cc + cg];
            half4 o;
            #pragma unroll
            for (int r = 0; r < 4; ++r)
                o[r] = (half_t)((float)hv[r] - acc[ti][tj][r] * csr[tj]);
            *(half4*)&sD[(size_t)mr * 256 + cc * 8 + sub] = o;
        }
    }
    __syncthreads();   // sD complete (fb reads also done)

    // T phase: T[co][m] = sum_c tw[co][c] * d[m][c]; tw streamed from L2
    float4v acc2[4][2];
    #pragma unroll
    for (int i = 0; i < 4; ++i)
        #pragma unroll
        for (int j = 0; j < 2; ++j) acc2[i][j] = (float4v)0.f;
    #pragma unroll
    for (int ks = 0; ks < 8; ++ks) {
        half8 af[4], bf[2];
        #pragma unroll
        for (int tm = 0; tm < 4; ++tm)
            af[tm] = *(const half8*)&sD[(size_t)(tm * 16 + m16) * 256
                                        + (((ks * 4 + quad) ^ (m16 & 7)) * 8)];
        #pragma unroll
        for (int tc = 0; tc < 2; ++tc)
            bf[tc] = *(const half8*)&tw[(size_t)(wjT * 32 + tc * 16 + m16) * 256
                                        + ks * 32 + quad * 8];
        #pragma unroll
        for (int tm = 0; tm < 4; ++tm)
            #pragma unroll
            for (int tc = 0; tc < 2; ++tc)
                acc2[tm][tc] = __builtin_amdgcn_mfma_f32_16x16x32_f16(
                    af[tm], bf[tc], acc2[tm][tc], 0, 0, 0);
    }

    // epilogue: out = h + relu(bn(T + tb)); hNext fp16
    const long yB = (long)4 * Cc * Nn;
    float* yb = outL + (size_t)b * yB;
    half_t* hn = hNext ? hNext + (size_t)b * sNC : nullptr;
    #pragma unroll
    for (int tc = 0; tc < 2; ++tc) {
        const int co = wjT * 32 + tc * 16 + m16;
        const float tb2 = tb[co];
        const float sc2 = bng[co] * rsqrtf(bnv[co] + 1e-3f);
        const float sh2 = bnb[co] - bnm[co] * sc2;
        #pragma unroll
        for (int tm = 0; tm < 4; ++tm) {
            const int mg = j0 + tm * 16 + quad * 4;
            float4v o;
            #pragma unroll
            for (int r = 0; r < 4; ++r) {
                const float t2  = acc2[tm][tc][r] + tb2;
                const float rel = fmaxf(fmaf(t2, sc2, sh2), 0.f);
                const float hv  = (float)hb[(size_t)(mg + r) * Cc + co];
                const float ov  = hv + rel;
                o[r] = ov;
                if (hn) hn[(size_t)(mg + r) * Cc + co] = (half_t)ov;
            }
            *(float4v*)&yb[(size_t)co * Nn + mg] = o;
        }
    }
}

// x [B,C,N] fp32 -> xT [B,N,C] fp16
__global__ __launch_bounds__(256)
void xpose_cast(const float* __restrict__ x, half_t* __restrict__ xT)
{
    __shared__ half_t tile[32][33];
    const int tx = threadIdx.x & 31, ty = threadIdx.x >> 5;
    const int n0 = blockIdx.x * 32, c0 = blockIdx.y * 32, b = blockIdx.z;
    #pragma unroll
    for (int r = 0; r < 4; ++r)
        tile[ty * 4 + r][tx] =
            (half_t)x[((size_t)b * Cc + c0 + ty * 4 + r) * Nn + n0 + tx];
    __syncthreads();
    #pragma unroll
    for (int r = 0; r < 4; ++r)
        xT[((size_t)b * Nn + n0 + ty * 4 + r) * Cc + c0 + tx] = tile[tx][ty * 4 + r];
}

// single kernel casting all 5 weight tensors into one fp16 arena
__global__ __launch_bounds__(256)
void castall(const float* __restrict__ c1, const float* __restrict__ c2,
             const float* __restrict__ qk, const float* __restrict__ vw,
             const float* __restrict__ tw, half_t* __restrict__ dst)
{
    const int i = (blockIdx.x * 256 + threadIdx.x) * 4;   // grid 768 -> 786432 elems
    const float* s; int o;
    if      (i < 65536)  { s = c1; o = 0; }
    else if (i < 131072) { s = c2; o = 65536; }
    else if (i < 196608) { s = qk; o = 131072; }
    else if (i < 458752) { s = vw; o = 196608; }
    else                 { s = tw; o = 458752; }
    const float4v v = *(const float4v*)(s + (i - o));
    half4 out;
    #pragma unroll
    for (int r = 0; r < 4; ++r) out[r] = (half_t)v[r];
    *(half4*)(dst + i) = out;
}

extern "C" void kernel_launch(void* const* d_in, const int* in_sizes, int n_in,
                              void* d_out, int out_size, void* d_ws, size_t ws_size,
                              hipStream_t stream)
{
    const float* x    = (const float*)d_in[0];
    const float* c1w  = (const float*)d_in[1];
    const float* c2w  = (const float*)d_in[2];
    const float* bn1g = (const float*)d_in[3], *bn1b = (const float*)d_in[4];
    const float* bn1m = (const float*)d_in[5], *bn1v = (const float*)d_in[6];
    const float* bn2g = (const float*)d_in[7], *bn2b = (const float*)d_in[8];
    const float* bn2m = (const float*)d_in[9], *bn2v = (const float*)d_in[10];
    const float* qkw  = (const float*)d_in[11];
    const float* vw   = (const float*)d_in[12];
    const float* vb   = (const float*)d_in[13];
    const float* tw   = (const float*)d_in[14];
    const float* tb   = (const float*)d_in[15];
    const float* sag  = (const float*)d_in[16];
    const float* sab  = (const float*)d_in[17];
    const float* sam  = (const float*)d_in[18];
    const float* sav  = (const float*)d_in[19];
    float* out = (float*)d_out;

    // ---- workspace layout ----
    char* ws = (char*)d_ws;
    const size_t HSZ = (size_t)Bn * Nn * Cc * 2;          // 16 MB
    half_t* xT   = (half_t*)(ws);
    half_t* hA   = (half_t*)(ws + HSZ);
    half_t* hBuf = (half_t*)(ws + 2 * HSZ);
    half_t* q_s  = (half_t*)(ws + 3 * HSZ);               // 4 MB
    half_t* xv_s = (half_t*)(ws + 3 * HSZ + (size_t)4194304);       // 16 MB
    float*  Pbuf = (float*) (ws + 4 * HSZ + (size_t)4194304);       // 4 MB
    float*  offp = (float*) (ws + 4 * HSZ + (size_t)8388608);       // 128 KB
    half_t* warena = (half_t*)(ws + 4 * HSZ + (size_t)8519680);     // 1.5 MB
    half_t* wc1  = warena;
    half_t* wc2  = wc1 + 65536;
    half_t* wqk  = wc2 + 65536;
    half_t* wv   = wqk + 65536;
    half_t* wt   = wv  + 262144;

    dim3 blk(256);

    castall<<<768, blk, 0, stream>>>(c1w, c2w, qkw, vw, tw, warena);
    xpose_cast<<<dim3(Nn / 32, Cc / 32, Bn), blk, 0, stream>>>(x, xT);

    mgemm<EPI_H, 256, 128, 4, 2, false><<<dim3(16, 1, Bn), dim3(512), 0, stream>>>(
        wc1, 0, xT, sNC, hA, sNC, Cc,
        nullptr, bn1g, bn1b, bn1m, bn1v, Cc);
    mgemm<EPI_H, 256, 128, 4, 2, false><<<dim3(16, 1, Bn), dim3(512), 0, stream>>>(
        wc2, 0, hA, sNC, hBuf, sNC, Cc,
        nullptr, bn2g, bn2b, bn2m, bn2v, Cc);

    half_t* hcur = hBuf;
    half_t* hnxt = hA;
    for (int L = 0; L < 4; ++L) {
        mgemm<EPI_RAW, 64, 256, 1, 4, false><<<dim3(8, 1, Bn), blk, 0, stream>>>(
            wqk + (long)L * C4 * Cc, 0, hcur, sNC, q_s, sNQ, C4,
            nullptr, nullptr, nullptr, nullptr, nullptr, Cc);
        // softmax stats (parallel, proven) + tiny merge -> offp
        estats<<<dim3(16, 16, Bn), blk, 0, stream>>>(q_s, Pbuf);
        statsreduce<<<128, blk, 0, stream>>>(Pbuf, offp);
        mgemm<EPI_XV, 128, 256, 2, 4, true><<<dim3(1, 16, Bn), dim3(512), 0, stream>>>(
            hcur, sNC, wv + (long)L * Cc * Cc, 0, xv_s, (long)Cc * Nn, Nn,
            vb + L * Cc, nullptr, nullptr, nullptr, nullptr, Cc);
        flashxr<<<dim3(512), dim3(512), 0, stream>>>(
            q_s, xv_s, hcur, offp,
            wt + (long)L * Cc * Cc, tb + L * Cc,
            sag + L * Cc, sab + L * Cc, sam + L * Cc, sav + L * Cc,
            out + (long)L * Cc * Nn, (L < 3) ? hnxt : nullptr);
        half_t* tmp = hcur; hcur = hnxt; hnxt = tmp;
    }
}

// Round 12
// 713.726 us; speedup vs baseline: 1.4425x; 1.4425x over previous
//
#include <hip/hip_runtime.h>
#include <hip/hip_bf16.h>
#include <hip/hip_fp16.h>

// Problem constants: B=16, C=256, N=2048, NUM_SA=4
static constexpr int Bn = 16;
static constexpr int Cc = 256;
static constexpr int Nn = 2048;
static constexpr int C4 = 64;
static constexpr float LOG2E = 1.4426950408889634f;

typedef _Float16 half_t;
typedef __attribute__((ext_vector_type(8))) _Float16 half8;
typedef __attribute__((ext_vector_type(4))) _Float16 half4;
typedef __attribute__((ext_vector_type(8))) short short8;
typedef __attribute__((ext_vector_type(4))) float float4v;

static constexpr long sNC = (long)Nn * Cc;   // 524288
static constexpr long sNQ = (long)Nn * C4;   // 131072

#define DEVI __device__ __forceinline__

DEVI float bf2f(unsigned short u) { return __uint_as_float(((unsigned)u) << 16); }
DEVI unsigned short f2bf(float f) {
    unsigned x = __float_as_uint(f);
    x += 0x7fffu + ((x >> 16) & 1u);   // RNE
    return (unsigned short)(x >> 16);
}

// async global->LDS, 16B per lane. LDS dest = wave-uniform base + lane*16.
DEVI void gload16(const void* g, void* l) {
    __builtin_amdgcn_global_load_lds(
        (const __attribute__((address_space(1))) unsigned int*)g,
        (__attribute__((address_space(3))) unsigned int*)l, 16, 0, 0);
}

enum { EPI_RAW = 0, EPI_H = 1, EPI_XV = 2 };

// Canonical MFMA GEMM: Y[j][i] = epi( sum_k A[i*K+k] * B[j*K+k] )
template<int MODE, int BM, int BN, int WI, int WJ, bool BF16OUT>
__global__ __launch_bounds__(WI * WJ * 64)
void mgemm(const half_t* __restrict__ A, long aB,
           const half_t* __restrict__ Bm, long bB,
           void* __restrict__ Yv, long yB, int ldy,
           const float* __restrict__ bias,
           const float* __restrict__ bng, const float* __restrict__ bnb,
           const float* __restrict__ bnm, const float* __restrict__ bnv,
           int K)
{
    constexpr int NW = WI * WJ;
    __shared__ __align__(16) half_t Als[2][BM][32];
    __shared__ __align__(16) half_t Bls[2][BN][32];

    const int tid  = threadIdx.x;
    const int w    = tid >> 6;
    const int lane = tid & 63;
    const int wi   = w % WI;
    const int wj   = w / WI;
    const int quad = lane >> 4, m16 = lane & 15;
    const int lr   = lane >> 2, lc = lane & 3;
    const int b    = blockIdx.z;
    const int j0   = blockIdx.x * BN;
    const int i0   = blockIdx.y * BM;

    const half_t* Ab = A + (size_t)b * aB;
    const half_t* Bb = Bm + (size_t)b * bB;

    float4v acc[4][4];
    #pragma unroll
    for (int i = 0; i < 4; ++i)
        #pragma unroll
        for (int j = 0; j < 4; ++j) acc[i][j] = (float4v)0.f;

    for (int k0 = 0; k0 < K; k0 += 64) {
        #pragma unroll
        for (int s = 0; s < 2; ++s) {
            const int kk = k0 + s * 32 + lc * 8;
            #pragma unroll
            for (int t = 0; t < BM / (16 * NW); ++t) {
                const int row = (t * NW + w) * 16;
                gload16(Ab + (size_t)(i0 + row + lr) * K + kk, &Als[s][row][0]);
            }
            #pragma unroll
            for (int t = 0; t < BN / (16 * NW); ++t) {
                const int row = (t * NW + w) * 16;
                gload16(Bb + (size_t)(j0 + row + lr) * K + kk, &Bls[s][row][0]);
            }
        }
        __syncthreads();
        #pragma unroll
        for (int s = 0; s < 2; ++s) {
            half8 af[4], bf[4];
            #pragma unroll
            for (int t = 0; t < 4; ++t)
                af[t] = *(const half8*)&Als[s][wi * 64 + t * 16 + m16][quad * 8];
            #pragma unroll
            for (int t = 0; t < 4; ++t)
                bf[t] = *(const half8*)&Bls[s][wj * 64 + t * 16 + m16][quad * 8];
            #pragma unroll
            for (int ti = 0; ti < 4; ++ti)
                #pragma unroll
                for (int tj = 0; tj < 4; ++tj)
                    acc[ti][tj] = __builtin_amdgcn_mfma_f32_16x16x32_f16(
                        af[ti], bf[tj], acc[ti][tj], 0, 0, 0);
        }
        __syncthreads();
    }

    #pragma unroll
    for (int ti = 0; ti < 4; ++ti) {
        const int il = i0 + wi * 64 + ti * 16 + quad * 4;
        #pragma unroll
        for (int tj = 0; tj < 4; ++tj) {
            const int jl = j0 + wj * 64 + tj * 16 + m16;
            float4v v = acc[ti][tj];
            if (MODE == EPI_RAW) {
                half4 o;
                #pragma unroll
                for (int r = 0; r < 4; ++r) o[r] = (half_t)v[r];
                *(half4*)((half_t*)Yv + (size_t)b * yB + (size_t)jl * ldy + il) = o;
            } else if (MODE == EPI_H) {
                half4 o;
                #pragma unroll
                for (int r = 0; r < 4; ++r) {
                    const float sc = bng[il + r] * rsqrtf(bnv[il + r] + 1e-3f);
                    const float sh = bnb[il + r] - bnm[il + r] * sc;
                    o[r] = (half_t)fmaxf(fmaf(v[r], sc, sh), 0.f);
                }
                *(half4*)((half_t*)Yv + (size_t)b * yB + (size_t)jl * ldy + il) = o;
            } else {   // EPI_XV
                const float bj = bias[jl];
                if (BF16OUT) {
                    ushort4 o;
                    o.x = f2bf(v[0] + bj); o.y = f2bf(v[1] + bj);
                    o.z = f2bf(v[2] + bj); o.w = f2bf(v[3] + bj);
                    *(ushort4*)((unsigned short*)Yv + (size_t)b * yB + (size_t)jl * ldy + il) = o;
                } else {
                    half4 o;
                    #pragma unroll
                    for (int r = 0; r < 4; ++r) o[r] = (half_t)(v[r] + bj);
                    *(half4*)((half_t*)Yv + (size_t)b * yB + (size_t)jl * ldy + il) = o;
                }
            }
        }
    }
}

// Pass 1: E = q q^T tile stats (no E store) -> Pbuf[b][m][16 iblk][2].
// PROVEN parallel version: (16,16,Bn) grid.
__global__ __launch_bounds__(256)
void estats(const half_t* __restrict__ q, float* __restrict__ Pbuf)
{
    __shared__ __align__(16) half_t sA[128 * 64];
    __shared__ __align__(16) half_t sB[128 * 64];
    __shared__ float red[2][2][4][16][2];
    const int tid = threadIdx.x, w = tid >> 6, lane = tid & 63;
    const int wi = w & 1, wj = w >> 1, quad = lane >> 4, m16 = lane & 15;
    const int b = blockIdx.z, j0 = blockIdx.x * 128, i0 = blockIdx.y * 128;
    const half_t* qb = q + (size_t)b * sNQ;

    #pragma unroll
    for (int t = 0; t < 4; ++t) {
        const int g = w * 256 + t * 64 + lane;
        const int r = g >> 3, c = g & 7;
        const int cs = c ^ (r & 7);
        gload16(qb + (size_t)(i0 + r) * 64 + cs * 8, sA + (w * 256 + t * 64) * 8);
        gload16(qb + (size_t)(j0 + r) * 64 + cs * 8, sB + (w * 256 + t * 64) * 8);
    }
    __syncthreads();

    half8 an[4][2], bm[4][2];
    #pragma unroll
    for (int t = 0; t < 4; ++t)
        #pragma unroll
        for (int ks = 0; ks < 2; ++ks) {
            const int pc = ((ks * 4 + quad) ^ (m16 & 7)) * 8;
            an[t][ks] = *(const half8*)&sA[(wi * 64 + t * 16 + m16) * 64 + pc];
            bm[t][ks] = *(const half8*)&sB[(wj * 64 + t * 16 + m16) * 64 + pc];
        }

    #pragma unroll
    for (int tj = 0; tj < 4; ++tj) {
        float4v e[4];
        #pragma unroll
        for (int ti = 0; ti < 4; ++ti) {
            e[ti] = (float4v)0.f;
            e[ti] = __builtin_amdgcn_mfma_f32_16x16x32_f16(an[ti][0], bm[tj][0], e[ti], 0, 0, 0);
            e[ti] = __builtin_amdgcn_mfma_f32_16x16x32_f16(an[ti][1], bm[tj][1], e[ti], 0, 0, 0);
        }
        float lmax = -1e30f;
        #pragma unroll
        for (int ti = 0; ti < 4; ++ti)
            #pragma unroll
            for (int r = 0; r < 4; ++r) lmax = fmaxf(lmax, e[ti][r]);
        lmax = fmaxf(lmax, __shfl_xor(lmax, 16));
        lmax = fmaxf(lmax, __shfl_xor(lmax, 32));
        float ls = 0.f;
        #pragma unroll
        for (int ti = 0; ti < 4; ++ti)
            #pragma unroll
            for (int r = 0; r < 4; ++r) ls += __expf(e[ti][r] - lmax);
        ls += __shfl_xor(ls, 16);
        ls += __shfl_xor(ls, 32);
        if (quad == 0) { red[wi][wj][tj][m16][0] = lmax; red[wi][wj][tj][m16][1] = ls; }
    }
    __syncthreads();
    if (tid < 128) {
        const int wj2 = tid >> 6, tj2 = (tid >> 4) & 3, mm = tid & 15;
        const float m0 = red[0][wj2][tj2][mm][0], s0 = red[0][wj2][tj2][mm][1];
        const float m1 = red[1][wj2][tj2][mm][0], s1 = red[1][wj2][tj2][mm][1];
        const float M = fmaxf(m0, m1);
        const float S = s0 * __expf(m0 - M) + s1 * __expf(m1 - M);
        const int m = j0 + wj2 * 64 + tj2 * 16 + mm;
        *(float2*)(Pbuf + (((size_t)b * Nn + m) * 16 + blockIdx.y) * 2) = make_float2(M, S);
    }
}

// Merge 16 per-block partials -> off[b][m] = m*log2e + log2(S)
__global__ __launch_bounds__(256)
void statsreduce(const float* __restrict__ Pbuf, float* __restrict__ off)
{
    const int id = blockIdx.x * 256 + threadIdx.x;   // 0..32767
    const int b = id >> 11, m = id & 2047;
    const float2* p = (const float2*)(Pbuf + ((size_t)b * Nn + m) * 32);
    float M = -1e30f;
    #pragma unroll
    for (int i = 0; i < 16; ++i) M = fmaxf(M, p[i].x);
    float S = 0.f;
    #pragma unroll
    for (int i = 0; i < 16; ++i) S += p[i].y * __expf(p[i].x - M);
    off[(size_t)b * Nn + m] = fmaf(M, LOG2E, __log2f(S));
}

// Pass 2: fused attention-apply + t-GEMM + epilogue (ROUND-10 version,
// measured 84.7 us -- best). 512 threads (8 waves), 1 block per
// (b, m-64-tile) -> 512 blocks, 64 KB LDS -> 2 co-resident blocks/CU.
// q staged via gload16->sQA LDS double-buffer one chunk ahead (register
// buffering regressed 2x in r11: naked global loads serialize the block).
// Prologue loads off[] directly (8 KB, one gload16/thread).
__global__ __launch_bounds__(512)
void flashxr(const half_t* __restrict__ q, const half_t* __restrict__ xv,
             const half_t* __restrict__ h, const float* __restrict__ offp,
             const half_t* __restrict__ tw, const float* __restrict__ tb,
             const float* __restrict__ bng, const float* __restrict__ bnb,
             const float* __restrict__ bnm, const float* __restrict__ bnv,
             float* __restrict__ outL, half_t* __restrict__ hNext)
{
    __shared__ __align__(16) half_t sXV[256 * 64];    // 32 KB; reused as sD[64][256]
    __shared__ __align__(16) half_t sQA[2][64 * 64];  // 16 KB, next-chunk dbuf
    __shared__ __align__(16) half_t sP[64 * 64];      // 8 KB: P tile / cs buf
    __shared__ float sOff[Nn];                        // 8 KB

    const int tid = threadIdx.x, w = tid >> 6, lane = tid & 63;
    const int quad = lane >> 4, m16 = lane & 15;
    const int wiE = w & 1, wjE = w >> 1;        // E: n-32-half, m-16-tile (4)
    const int wi = w & 3, wj = w >> 2;          // XR: c-64-tile (4), m-32-tile (2)
    const int wjT = w;                          // T: co-32-tile (8)
    const int f = blockIdx.x;
    const int W = (f & 7) * 64 + (f >> 3);      // bijective over [0,512)
    const int b = W >> 5, j0 = (W & 31) * 64;
    const half_t* qb  = q + (size_t)b * sNQ;
    const half_t* xvb = xv + (size_t)b * sNC;   // [256][2048] half bits

    const int sr = tid >> 3, sc = tid & 7;      // 64-row staging coords (sQA)
    const int qsw = (sc ^ (sr & 7)) * 8;

    // ---- prologue: stage sQA[0] + sOff (8 KB = 512 x 16B); bq regs ----
    gload16(qb + (size_t)sr * 64 + qsw, &sQA[0][(size_t)tid * 8]);
    gload16(offp + (size_t)b * Nn + (size_t)tid * 4, sOff + (size_t)tid * 4);

    half8 bq[2];
    #pragma unroll
    for (int s = 0; s < 2; ++s)
        bq[s] = *(const half8*)(qb + (size_t)(j0 + wjE * 16 + m16) * 64 + (s * 4 + quad) * 8);

    __syncthreads();   // drains sQA[0] + sOff stages

    float4v acc[4][2];
    #pragma unroll
    for (int i = 0; i < 4; ++i)
        #pragma unroll
        for (int j = 0; j < 2; ++j) acc[i][j] = (float4v)0.f;
    float csa = 0.f;
    const int mrow = wjE * 16 + m16;

    for (int nc = 0; nc < 32; ++nc) {
        // stage sXV for THIS chunk (prev XR done at loop-end barrier);
        // stage NEXT chunk's q rows into the other sQA buffer
        #pragma unroll
        for (int t = 0; t < 4; ++t) {
            const int g = t * 512 + tid;
            const int r = g >> 3, c = g & 7;
            gload16(xvb + (size_t)r * Nn + nc * 64 + ((c ^ (r & 7)) * 8),
                    sXV + (size_t)g * 8);
        }
        if (nc < 31)
            gload16(qb + (size_t)((nc + 1) * 64 + sr) * 64 + qsw,
                    &sQA[(nc + 1) & 1][(size_t)tid * 8]);
        __syncthreads();   // drains own stages; sibling block overlaps stall

        // E phase from sQA[nc&1] (staged previous chunk)
        const half_t* qA = &sQA[nc & 1][0];
        const int nbase = nc * 64 + wiE * 32 + quad * 4;
        #pragma unroll
        for (int ti = 0; ti < 2; ++ti) {
            const int nl = wiE * 32 + ti * 16 + m16;
            const half8 an0 = *(const half8*)&qA[(size_t)nl * 64 + ((quad ^ (m16 & 7)) * 8)];
            const half8 an1 = *(const half8*)&qA[(size_t)nl * 64 + (((4 + quad) ^ (m16 & 7)) * 8)];
            float4v e = (float4v)0.f;
            e = __builtin_amdgcn_mfma_f32_16x16x32_f16(an0, bq[0], e, 0, 0, 0);
            e = __builtin_amdgcn_mfma_f32_16x16x32_f16(an1, bq[1], e, 0, 0, 0);
            const float4v o4 = *(const float4v*)&sOff[nbase + ti * 16];
            float c0 = 0.f; ushort4 pk;
            #pragma unroll
            for (int r = 0; r < 4; ++r) {
                const float p = __builtin_amdgcn_exp2f(fmaf(e[r], LOG2E, -o4[r]));
                c0 += p; (&pk.x)[r] = f2bf(p);
            }
            csa += c0;
            const int pc = (wiE * 4 + ti * 2 + (quad >> 1)) ^ (m16 & 7);
            *(ushort4*)&((unsigned short*)sP)[(size_t)mrow * 64 + pc * 8 + (quad & 1) * 4] = pk;
        }
        __syncthreads();   // publishes sP

        // XR phase: acc[c][m] += xv[c][k=n] * P[m][k=n], K = 64
        #pragma unroll
        for (int ks = 0; ks < 2; ++ks) {
            short8 xa[4], pb[2];
            #pragma unroll
            for (int ti = 0; ti < 4; ++ti)
                xa[ti] = *(const short8*)&sXV[(size_t)(wi * 64 + ti * 16 + m16) * 64
                                              + (((ks * 4 + quad) ^ (m16 & 7)) * 8)];
            #pragma unroll
            for (int tj = 0; tj < 2; ++tj)
                pb[tj] = *(const short8*)&sP[(size_t)(wj * 32 + tj * 16 + m16) * 64
                                             + (((ks * 4 + quad) ^ (m16 & 7)) * 8)];
            __builtin_amdgcn_s_setprio(1);
            #pragma unroll
            for (int ti = 0; ti < 4; ++ti)
                #pragma unroll
                for (int tj = 0; tj < 2; ++tj)
                    acc[ti][tj] = __builtin_amdgcn_mfma_f32_16x16x32_bf16(
                        xa[ti], pb[tj], acc[ti][tj], 0, 0, 0);
            __builtin_amdgcn_s_setprio(0);
        }
        __syncthreads();   // XR reads done before next chunk overwrites
    }

    // colsum reduce: quad butterfly, then cross-wiE via LDS (sP as floats)
    csa += __shfl_xor(csa, 16);
    csa += __shfl_xor(csa, 32);
    float* fb = (float*)sP;
    if (lane < 16) fb[wiE * 64 + wjE * 16 + lane] = csa;
    __syncthreads();
    float csr[2];
    #pragma unroll
    for (int tj = 0; tj < 2; ++tj) {
        const int m = wj * 32 + tj * 16 + m16;
        csr[tj] = 1.0f / (1e-9f + fb[m] + fb[64 + m]);
    }

    // d = h - xr*csr -> sD (fp16, swizzled [64 m][256 c], overlays sXV)
    const half_t* hb = h + (size_t)b * sNC;
    half_t* sD = sXV;
    #pragma unroll
    for (int ti = 0; ti < 4; ++ti) {
        const int cg = wi * 64 + ti * 16 + quad * 4;
        const int cc = (cg >> 3) ^ (m16 & 7);      // swizzled 16B chunk
        const int sub = (quad & 1) * 4;
        #pragma unroll
        for (int tj = 0; tj < 2; ++tj) {
            const int mr = wj * 32 + tj * 16 + m16;
            const int mg = j0 + mr;
            const half4 hv = *(const half4*)&hb[(size_t)mg * Cc + cg];
            half4 o;
            #pragma unroll
            for (int r = 0; r < 4; ++r)
                o[r] = (half_t)((float)hv[r] - acc[ti][tj][r] * csr[tj]);
            *(half4*)&sD[(size_t)mr * 256 + cc * 8 + sub] = o;
        }
    }
    __syncthreads();   // sD complete (fb reads also done)

    // T phase: T[co][m] = sum_c tw[co][c] * d[m][c]; tw streamed from L2
    float4v acc2[4][2];
    #pragma unroll
    for (int i = 0; i < 4; ++i)
        #pragma unroll
        for (int j = 0; j < 2; ++j) acc2[i][j] = (float4v)0.f;
    #pragma unroll
    for (int ks = 0; ks < 8; ++ks) {
        half8 af[4], bf[2];
        #pragma unroll
        for (int tm = 0; tm < 4; ++tm)
            af[tm] = *(const half8*)&sD[(size_t)(tm * 16 + m16) * 256
                                        + (((ks * 4 + quad) ^ (m16 & 7)) * 8)];
        #pragma unroll
        for (int tc = 0; tc < 2; ++tc)
            bf[tc] = *(const half8*)&tw[(size_t)(wjT * 32 + tc * 16 + m16) * 256
                                        + ks * 32 + quad * 8];
        #pragma unroll
        for (int tm = 0; tm < 4; ++tm)
            #pragma unroll
            for (int tc = 0; tc < 2; ++tc)
                acc2[tm][tc] = __builtin_amdgcn_mfma_f32_16x16x32_f16(
                    af[tm], bf[tc], acc2[tm][tc], 0, 0, 0);
    }

    // epilogue: out = h + relu(bn(T + tb)); hNext fp16
    const long yB = (long)4 * Cc * Nn;
    float* yb = outL + (size_t)b * yB;
    half_t* hn = hNext ? hNext + (size_t)b * sNC : nullptr;
    #pragma unroll
    for (int tc = 0; tc < 2; ++tc) {
        const int co = wjT * 32 + tc * 16 + m16;
        const float tb2 = tb[co];
        const float sc2 = bng[co] * rsqrtf(bnv[co] + 1e-3f);
        const float sh2 = bnb[co] - bnm[co] * sc2;
        #pragma unroll
        for (int tm = 0; tm < 4; ++tm) {
            const int mg = j0 + tm * 16 + quad * 4;
            float4v o;
            #pragma unroll
            for (int r = 0; r < 4; ++r) {
                const float t2  = acc2[tm][tc][r] + tb2;
                const float rel = fmaxf(fmaf(t2, sc2, sh2), 0.f);
                const float hv  = (float)hb[(size_t)(mg + r) * Cc + co];
                const float ov  = hv + rel;
                o[r] = ov;
                if (hn) hn[(size_t)(mg + r) * Cc + co] = (half_t)ov;
            }
            *(float4v*)&yb[(size_t)co * Nn + mg] = o;
        }
    }
}

// x [B,C,N] fp32 -> xT [B,N,C] fp16
__global__ __launch_bounds__(256)
void xpose_cast(const float* __restrict__ x, half_t* __restrict__ xT)
{
    __shared__ half_t tile[32][33];
    const int tx = threadIdx.x & 31, ty = threadIdx.x >> 5;
    const int n0 = blockIdx.x * 32, c0 = blockIdx.y * 32, b = blockIdx.z;
    #pragma unroll
    for (int r = 0; r < 4; ++r)
        tile[ty * 4 + r][tx] =
            (half_t)x[((size_t)b * Cc + c0 + ty * 4 + r) * Nn + n0 + tx];
    __syncthreads();
    #pragma unroll
    for (int r = 0; r < 4; ++r)
        xT[((size_t)b * Nn + n0 + ty * 4 + r) * Cc + c0 + tx] = tile[tx][ty * 4 + r];
}

// single kernel casting all 5 weight tensors into one fp16 arena
__global__ __launch_bounds__(256)
void castall(const float* __restrict__ c1, const float* __restrict__ c2,
             const float* __restrict__ qk, const float* __restrict__ vw,
             const float* __restrict__ tw, half_t* __restrict__ dst)
{
    const int i = (blockIdx.x * 256 + threadIdx.x) * 4;   // grid 768 -> 786432 elems
    const float* s; int o;
    if      (i < 65536)  { s = c1; o = 0; }
    else if (i < 131072) { s = c2; o = 65536; }
    else if (i < 196608) { s = qk; o = 131072; }
    else if (i < 458752) { s = vw; o = 196608; }
    else                 { s = tw; o = 458752; }
    const float4v v = *(const float4v*)(s + (i - o));
    half4 out;
    #pragma unroll
    for (int r = 0; r < 4; ++r) out[r] = (half_t)v[r];
    *(half4*)(dst + i) = out;
}

extern "C" void kernel_launch(void* const* d_in, const int* in_sizes, int n_in,
                              void* d_out, int out_size, void* d_ws, size_t ws_size,
                              hipStream_t stream)
{
    const float* x    = (const float*)d_in[0];
    const float* c1w  = (const float*)d_in[1];
    const float* c2w  = (const float*)d_in[2];
    const float* bn1g = (const float*)d_in[3], *bn1b = (const float*)d_in[4];
    const float* bn1m = (const float*)d_in[5], *bn1v = (const float*)d_in[6];
    const float* bn2g = (const float*)d_in[7], *bn2b = (const float*)d_in[8];
    const float* bn2m = (const float*)d_in[9], *bn2v = (const float*)d_in[10];
    const float* qkw  = (const float*)d_in[11];
    const float* vw   = (const float*)d_in[12];
    const float* vb   = (const float*)d_in[13];
    const float* tw   = (const float*)d_in[14];
    const float* tb   = (const float*)d_in[15];
    const float* sag  = (const float*)d_in[16];
    const float* sab  = (const float*)d_in[17];
    const float* sam  = (const float*)d_in[18];
    const float* sav  = (const float*)d_in[19];
    float* out = (float*)d_out;

    // ---- workspace layout ----
    char* ws = (char*)d_ws;
    const size_t HSZ = (size_t)Bn * Nn * Cc * 2;          // 16 MB
    half_t* xT   = (half_t*)(ws);
    half_t* hA   = (half_t*)(ws + HSZ);
    half_t* hBuf = (half_t*)(ws + 2 * HSZ);
    half_t* q_s  = (half_t*)(ws + 3 * HSZ);               // 4 MB
    half_t* xv_s = (half_t*)(ws + 3 * HSZ + (size_t)4194304);       // 16 MB
    float*  Pbuf = (float*) (ws + 4 * HSZ + (size_t)4194304);       // 4 MB
    float*  offp = (float*) (ws + 4 * HSZ + (size_t)8388608);       // 128 KB
    half_t* warena = (half_t*)(ws + 4 * HSZ + (size_t)8519680);     // 1.5 MB
    half_t* wc1  = warena;
    half_t* wc2  = wc1 + 65536;
    half_t* wqk  = wc2 + 65536;
    half_t* wv   = wqk + 65536;
    half_t* wt   = wv  + 262144;

    dim3 blk(256);

    castall<<<768, blk, 0, stream>>>(c1w, c2w, qkw, vw, tw, warena);
    xpose_cast<<<dim3(Nn / 32, Cc / 32, Bn), blk, 0, stream>>>(x, xT);

    mgemm<EPI_H, 256, 128, 4, 2, false><<<dim3(16, 1, Bn), dim3(512), 0, stream>>>(
        wc1, 0, xT, sNC, hA, sNC, Cc,
        nullptr, bn1g, bn1b, bn1m, bn1v, Cc);
    mgemm<EPI_H, 256, 128, 4, 2, false><<<dim3(16, 1, Bn), dim3(512), 0, stream>>>(
        wc2, 0, hA, sNC, hBuf, sNC, Cc,
        nullptr, bn2g, bn2b, bn2m, bn2v, Cc);

    half_t* hcur = hBuf;
    half_t* hnxt = hA;
    for (int L = 0; L < 4; ++L) {
        mgemm<EPI_RAW, 64, 256, 1, 4, false><<<dim3(8, 1, Bn), blk, 0, stream>>>(
            wqk + (long)L * C4 * Cc, 0, hcur, sNC, q_s, sNQ, C4,
            nullptr, nullptr, nullptr, nullptr, nullptr, Cc);
        // softmax stats (parallel, proven) + tiny merge -> offp
        estats<<<dim3(16, 16, Bn), blk, 0, stream>>>(q_s, Pbuf);
        statsreduce<<<128, blk, 0, stream>>>(Pbuf, offp);
        mgemm<EPI_XV, 128, 256, 2, 4, true><<<dim3(1, 16, Bn), dim3(512), 0, stream>>>(
            hcur, sNC, wv + (long)L * Cc * Cc, 0, xv_s, (long)Cc * Nn, Nn,
            vb + L * Cc, nullptr, nullptr, nullptr, nullptr, Cc);
        flashxr<<<dim3(512), dim3(512), 0, stream>>>(
            q_s, xv_s, hcur, offp,
            wt + (long)L * Cc * Cc, tb + L * Cc,
            sag + L * Cc, sab + L * Cc, sam + L * Cc, sav + L * Cc,
            out + (long)L * Cc * Nn, (L < 3) ? hnxt : nullptr);
        half_t* tmp = hcur; hcur = hnxt; hnxt = tmp;
    }
}

// Round 13
// 677.390 us; speedup vs baseline: 1.5199x; 1.0536x over previous
//
#include <hip/hip_runtime.h>
#include <hip/hip_bf16.h>
#include <hip/hip_fp16.h>

// Problem constants: B=16, C=256, N=2048, NUM_SA=4
static constexpr int Bn = 16;
static constexpr int Cc = 256;
static constexpr int Nn = 2048;
static constexpr int C4 = 64;
static constexpr float LOG2E = 1.4426950408889634f;

typedef _Float16 half_t;
typedef __attribute__((ext_vector_type(8))) _Float16 half8;
typedef __attribute__((ext_vector_type(4))) _Float16 half4;
typedef __attribute__((ext_vector_type(8))) short short8;
typedef __attribute__((ext_vector_type(4))) float float4v;

static constexpr long sNC = (long)Nn * Cc;   // 524288
static constexpr long sNQ = (long)Nn * C4;   // 131072

#define DEVI __device__ __forceinline__

DEVI float bf2f(unsigned short u) { return __uint_as_float(((unsigned)u) << 16); }
DEVI unsigned short f2bf(float f) {
    unsigned x = __float_as_uint(f);
    x += 0x7fffu + ((x >> 16) & 1u);   // RNE
    return (unsigned short)(x >> 16);
}

// async global->LDS, 16B per lane. LDS dest = wave-uniform base + lane*16.
DEVI void gload16(const void* g, void* l) {
    __builtin_amdgcn_global_load_lds(
        (const __attribute__((address_space(1))) unsigned int*)g,
        (__attribute__((address_space(3))) unsigned int*)l, 16, 0, 0);
}

enum { EPI_RAW = 0, EPI_H = 1, EPI_XV = 2 };

// Canonical MFMA GEMM: Y[j][i] = epi( sum_k A[i*K+k] * B[j*K+k] )
// EPI_XV additionally folds the statsreduce (Pbuf 16-partial merge -> offp):
// 256 blocks x 128 outputs = 32768 off entries, done by tid<128 before the
// first staging barrier (hidden under stage drain). Stream order guarantees
// Pbuf complete (estats before) and offp consumed after (flashxr).
template<int MODE, int BM, int BN, int WI, int WJ, bool BF16OUT>
__global__ __launch_bounds__(WI * WJ * 64)
void mgemm(const half_t* __restrict__ A, long aB,
           const half_t* __restrict__ Bm, long bB,
           void* __restrict__ Yv, long yB, int ldy,
           const float* __restrict__ bias,
           const float* __restrict__ bng, const float* __restrict__ bnb,
           const float* __restrict__ bnm, const float* __restrict__ bnv,
           int K,
           const float* __restrict__ Pbuf, float* __restrict__ offp)
{
    constexpr int NW = WI * WJ;
    __shared__ __align__(16) half_t Als[2][BM][32];
    __shared__ __align__(16) half_t Bls[2][BN][32];

    const int tid  = threadIdx.x;
    const int w    = tid >> 6;
    const int lane = tid & 63;
    const int wi   = w % WI;
    const int wj   = w / WI;
    const int quad = lane >> 4, m16 = lane & 15;
    const int lr   = lane >> 2, lc = lane & 3;
    const int b    = blockIdx.z;
    const int j0   = blockIdx.x * BN;
    const int i0   = blockIdx.y * BM;

    const half_t* Ab = A + (size_t)b * aB;
    const half_t* Bb = Bm + (size_t)b * bB;

    float4v acc[4][4];
    #pragma unroll
    for (int i = 0; i < 4; ++i)
        #pragma unroll
        for (int j = 0; j < 4; ++j) acc[i][j] = (float4v)0.f;

    bool first = true;
    for (int k0 = 0; k0 < K; k0 += 64) {
        #pragma unroll
        for (int s = 0; s < 2; ++s) {
            const int kk = k0 + s * 32 + lc * 8;
            #pragma unroll
            for (int t = 0; t < BM / (16 * NW); ++t) {
                const int row = (t * NW + w) * 16;
                gload16(Ab + (size_t)(i0 + row + lr) * K + kk, &Als[s][row][0]);
            }
            #pragma unroll
            for (int t = 0; t < BN / (16 * NW); ++t) {
                const int row = (t * NW + w) * 16;
                gload16(Bb + (size_t)(j0 + row + lr) * K + kk, &Bls[s][row][0]);
            }
        }
        // folded statsreduce (EPI_XV only, first iteration): hidden under
        // the stage drain of the first barrier
        if (MODE == EPI_XV && first && Pbuf && tid < 128) {
            const int m = blockIdx.y * 128 + tid;
            const float2* p = (const float2*)(Pbuf + ((size_t)b * Nn + m) * 32);
            float M = -1e30f;
            #pragma unroll
            for (int i = 0; i < 16; ++i) M = fmaxf(M, p[i].x);
            float S = 0.f;
            #pragma unroll
            for (int i = 0; i < 16; ++i) S += p[i].y * __expf(p[i].x - M);
            offp[(size_t)b * Nn + m] = fmaf(M, LOG2E, __log2f(S));
        }
        first = false;
        __syncthreads();
        #pragma unroll
        for (int s = 0; s < 2; ++s) {
            half8 af[4], bf[4];
            #pragma unroll
            for (int t = 0; t < 4; ++t)
                af[t] = *(const half8*)&Als[s][wi * 64 + t * 16 + m16][quad * 8];
            #pragma unroll
            for (int t = 0; t < 4; ++t)
                bf[t] = *(const half8*)&Bls[s][wj * 64 + t * 16 + m16][quad * 8];
            #pragma unroll
            for (int ti = 0; ti < 4; ++ti)
                #pragma unroll
                for (int tj = 0; tj < 4; ++tj)
                    acc[ti][tj] = __builtin_amdgcn_mfma_f32_16x16x32_f16(
                        af[ti], bf[tj], acc[ti][tj], 0, 0, 0);
        }
        __syncthreads();
    }

    #pragma unroll
    for (int ti = 0; ti < 4; ++ti) {
        const int il = i0 + wi * 64 + ti * 16 + quad * 4;
        #pragma unroll
        for (int tj = 0; tj < 4; ++tj) {
            const int jl = j0 + wj * 64 + tj * 16 + m16;
            float4v v = acc[ti][tj];
            if (MODE == EPI_RAW) {
                half4 o;
                #pragma unroll
                for (int r = 0; r < 4; ++r) o[r] = (half_t)v[r];
                *(half4*)((half_t*)Yv + (size_t)b * yB + (size_t)jl * ldy + il) = o;
            } else if (MODE == EPI_H) {
                half4 o;
                #pragma unroll
                for (int r = 0; r < 4; ++r) {
                    const float sc = bng[il + r] * rsqrtf(bnv[il + r] + 1e-3f);
                    const float sh = bnb[il + r] - bnm[il + r] * sc;
                    o[r] = (half_t)fmaxf(fmaf(v[r], sc, sh), 0.f);
                }
                *(half4*)((half_t*)Yv + (size_t)b * yB + (size_t)jl * ldy + il) = o;
            } else {   // EPI_XV
                const float bj = bias[jl];
                if (BF16OUT) {
                    ushort4 o;
                    o.x = f2bf(v[0] + bj); o.y = f2bf(v[1] + bj);
                    o.z = f2bf(v[2] + bj); o.w = f2bf(v[3] + bj);
                    *(ushort4*)((unsigned short*)Yv + (size_t)b * yB + (size_t)jl * ldy + il) = o;
                } else {
                    half4 o;
                    #pragma unroll
                    for (int r = 0; r < 4; ++r) o[r] = (half_t)(v[r] + bj);
                    *(half4*)((half_t*)Yv + (size_t)b * yB + (size_t)jl * ldy + il) = o;
                }
            }
        }
    }
}

// Pass 1: E = q q^T tile stats (no E store) -> Pbuf[b][m][16 iblk][2].
// PROVEN parallel version; now XCD-clustered: 1-D grid 4096, XCD r owns
// W in [512r, 512r+512) = batches {2r, 2r+1} -> per-XCD q working set is
// 8 MB (mostly L2-hit) instead of all 16 batches (L3-served).
__global__ __launch_bounds__(256)
void estats(const half_t* __restrict__ q, float* __restrict__ Pbuf)
{
    __shared__ __align__(16) half_t sA[128 * 64];
    __shared__ __align__(16) half_t sB[128 * 64];
    __shared__ float red[2][2][4][16][2];
    const int tid = threadIdx.x, w = tid >> 6, lane = tid & 63;
    const int wi = w & 1, wj = w >> 1, quad = lane >> 4, m16 = lane & 15;
    const int f = blockIdx.x;
    const int W = (f & 7) * 512 + (f >> 3);     // bijective over [0,4096)
    const int b = W >> 8;                       // 256 blocks per batch
    const int rem = W & 255;
    const int j0 = (rem & 15) * 128;            // column block
    const int ib = rem >> 4;                    // i-block index = Pbuf slot
    const int i0 = ib * 128;
    const half_t* qb = q + (size_t)b * sNQ;

    #pragma unroll
    for (int t = 0; t < 4; ++t) {
        const int g = w * 256 + t * 64 + lane;
        const int r = g >> 3, c = g & 7;
        const int cs = c ^ (r & 7);
        gload16(qb + (size_t)(i0 + r) * 64 + cs * 8, sA + (w * 256 + t * 64) * 8);
        gload16(qb + (size_t)(j0 + r) * 64 + cs * 8, sB + (w * 256 + t * 64) * 8);
    }
    __syncthreads();

    half8 an[4][2], bm[4][2];
    #pragma unroll
    for (int t = 0; t < 4; ++t)
        #pragma unroll
        for (int ks = 0; ks < 2; ++ks) {
            const int pc = ((ks * 4 + quad) ^ (m16 & 7)) * 8;
            an[t][ks] = *(const half8*)&sA[(wi * 64 + t * 16 + m16) * 64 + pc];
            bm[t][ks] = *(const half8*)&sB[(wj * 64 + t * 16 + m16) * 64 + pc];
        }

    #pragma unroll
    for (int tj = 0; tj < 4; ++tj) {
        float4v e[4];
        #pragma unroll
        for (int ti = 0; ti < 4; ++ti) {
            e[ti] = (float4v)0.f;
            e[ti] = __builtin_amdgcn_mfma_f32_16x16x32_f16(an[ti][0], bm[tj][0], e[ti], 0, 0, 0);
            e[ti] = __builtin_amdgcn_mfma_f32_16x16x32_f16(an[ti][1], bm[tj][1], e[ti], 0, 0, 0);
        }
        float lmax = -1e30f;
        #pragma unroll
        for (int ti = 0; ti < 4; ++ti)
            #pragma unroll
            for (int r = 0; r < 4; ++r) lmax = fmaxf(lmax, e[ti][r]);
        lmax = fmaxf(lmax, __shfl_xor(lmax, 16));
        lmax = fmaxf(lmax, __shfl_xor(lmax, 32));
        float ls = 0.f;
        #pragma unroll
        for (int ti = 0; ti < 4; ++ti)
            #pragma unroll
            for (int r = 0; r < 4; ++r) ls += __expf(e[ti][r] - lmax);
        ls += __shfl_xor(ls, 16);
        ls += __shfl_xor(ls, 32);
        if (quad == 0) { red[wi][wj][tj][m16][0] = lmax; red[wi][wj][tj][m16][1] = ls; }
    }
    __syncthreads();
    if (tid < 128) {
        const int wj2 = tid >> 6, tj2 = (tid >> 4) & 3, mm = tid & 15;
        const float m0 = red[0][wj2][tj2][mm][0], s0 = red[0][wj2][tj2][mm][1];
        const float m1 = red[1][wj2][tj2][mm][0], s1 = red[1][wj2][tj2][mm][1];
        const float M = fmaxf(m0, m1);
        const float S = s0 * __expf(m0 - M) + s1 * __expf(m1 - M);
        const int m = j0 + wj2 * 64 + tj2 * 16 + mm;
        *(float2*)(Pbuf + (((size_t)b * Nn + m) * 16 + ib) * 2) = make_float2(M, S);
    }
}

// Pass 2: fused attention-apply + t-GEMM + epilogue (round-10 body, measured
// 84.7 us -- best). 512 threads (8 waves), 1 block per (b, m-64-tile) ->
// 512 blocks, 64 KB LDS -> 2 co-resident blocks/CU. q staged via
// gload16->sQA LDS double-buffer (register buffering regressed 2x in r11).
__global__ __launch_bounds__(512)
void flashxr(const half_t* __restrict__ q, const half_t* __restrict__ xv,
             const half_t* __restrict__ h, const float* __restrict__ offp,
             const half_t* __restrict__ tw, const float* __restrict__ tb,
             const float* __restrict__ bng, const float* __restrict__ bnb,
             const float* __restrict__ bnm, const float* __restrict__ bnv,
             float* __restrict__ outL, half_t* __restrict__ hNext)
{
    __shared__ __align__(16) half_t sXV[256 * 64];    // 32 KB; reused as sD[64][256]
    __shared__ __align__(16) half_t sQA[2][64 * 64];  // 16 KB, next-chunk dbuf
    __shared__ __align__(16) half_t sP[64 * 64];      // 8 KB: P tile / cs buf
    __shared__ float sOff[Nn];                        // 8 KB

    const int tid = threadIdx.x, w = tid >> 6, lane = tid & 63;
    const int quad = lane >> 4, m16 = lane & 15;
    const int wiE = w & 1, wjE = w >> 1;        // E: n-32-half, m-16-tile (4)
    const int wi = w & 3, wj = w >> 2;          // XR: c-64-tile (4), m-32-tile (2)
    const int wjT = w;                          // T: co-32-tile (8)
    const int f = blockIdx.x;
    const int W = (f & 7) * 64 + (f >> 3);      // bijective over [0,512)
    const int b = W >> 5, j0 = (W & 31) * 64;
    const half_t* qb  = q + (size_t)b * sNQ;
    const half_t* xvb = xv + (size_t)b * sNC;   // [256][2048] half bits

    const int sr = tid >> 3, sc = tid & 7;      // 64-row staging coords (sQA)
    const int qsw = (sc ^ (sr & 7)) * 8;

    // ---- prologue: stage sQA[0] + sOff (8 KB = 512 x 16B); bq regs ----
    gload16(qb + (size_t)sr * 64 + qsw, &sQA[0][(size_t)tid * 8]);
    gload16(offp + (size_t)b * Nn + (size_t)tid * 4, sOff + (size_t)tid * 4);

    half8 bq[2];
    #pragma unroll
    for (int s = 0; s < 2; ++s)
        bq[s] = *(const half8*)(qb + (size_t)(j0 + wjE * 16 + m16) * 64 + (s * 4 + quad) * 8);

    __syncthreads();   // drains sQA[0] + sOff stages

    float4v acc[4][2];
    #pragma unroll
    for (int i = 0; i < 4; ++i)
        #pragma unroll
        for (int j = 0; j < 2; ++j) acc[i][j] = (float4v)0.f;
    float csa = 0.f;
    const int mrow = wjE * 16 + m16;

    for (int nc = 0; nc < 32; ++nc) {
        // stage sXV for THIS chunk (prev XR done at loop-end barrier);
        // stage NEXT chunk's q rows into the other sQA buffer
        #pragma unroll
        for (int t = 0; t < 4; ++t) {
            const int g = t * 512 + tid;
            const int r = g >> 3, c = g & 7;
            gload16(xvb + (size_t)r * Nn + nc * 64 + ((c ^ (r & 7)) * 8),
                    sXV + (size_t)g * 8);
        }
        if (nc < 31)
            gload16(qb + (size_t)((nc + 1) * 64 + sr) * 64 + qsw,
                    &sQA[(nc + 1) & 1][(size_t)tid * 8]);
        __syncthreads();   // drains own stages; sibling block overlaps stall

        // E phase from sQA[nc&1] (staged previous chunk)
        const half_t* qA = &sQA[nc & 1][0];
        const int nbase = nc * 64 + wiE * 32 + quad * 4;
        #pragma unroll
        for (int ti = 0; ti < 2; ++ti) {
            const int nl = wiE * 32 + ti * 16 + m16;
            const half8 an0 = *(const half8*)&qA[(size_t)nl * 64 + ((quad ^ (m16 & 7)) * 8)];
            const half8 an1 = *(const half8*)&qA[(size_t)nl * 64 + (((4 + quad) ^ (m16 & 7)) * 8)];
            float4v e = (float4v)0.f;
            e = __builtin_amdgcn_mfma_f32_16x16x32_f16(an0, bq[0], e, 0, 0, 0);
            e = __builtin_amdgcn_mfma_f32_16x16x32_f16(an1, bq[1], e, 0, 0, 0);
            const float4v o4 = *(const float4v*)&sOff[nbase + ti * 16];
            float c0 = 0.f; ushort4 pk;
            #pragma unroll
            for (int r = 0; r < 4; ++r) {
                const float p = __builtin_amdgcn_exp2f(fmaf(e[r], LOG2E, -o4[r]));
                c0 += p; (&pk.x)[r] = f2bf(p);
            }
            csa += c0;
            const int pc = (wiE * 4 + ti * 2 + (quad >> 1)) ^ (m16 & 7);
            *(ushort4*)&((unsigned short*)sP)[(size_t)mrow * 64 + pc * 8 + (quad & 1) * 4] = pk;
        }
        __syncthreads();   // publishes sP

        // XR phase: acc[c][m] += xv[c][k=n] * P[m][k=n], K = 64
        #pragma unroll
        for (int ks = 0; ks < 2; ++ks) {
            short8 xa[4], pb[2];
            #pragma unroll
            for (int ti = 0; ti < 4; ++ti)
                xa[ti] = *(const short8*)&sXV[(size_t)(wi * 64 + ti * 16 + m16) * 64
                                              + (((ks * 4 + quad) ^ (m16 & 7)) * 8)];
            #pragma unroll
            for (int tj = 0; tj < 2; ++tj)
                pb[tj] = *(const short8*)&sP[(size_t)(wj * 32 + tj * 16 + m16) * 64
                                             + (((ks * 4 + quad) ^ (m16 & 7)) * 8)];
            __builtin_amdgcn_s_setprio(1);
            #pragma unroll
            for (int ti = 0; ti < 4; ++ti)
                #pragma unroll
                for (int tj = 0; tj < 2; ++tj)
                    acc[ti][tj] = __builtin_amdgcn_mfma_f32_16x16x32_bf16(
                        xa[ti], pb[tj], acc[ti][tj], 0, 0, 0);
            __builtin_amdgcn_s_setprio(0);
        }
        __syncthreads();   // XR reads done before next chunk overwrites
    }

    // colsum reduce: quad butterfly, then cross-wiE via LDS (sP as floats)
    csa += __shfl_xor(csa, 16);
    csa += __shfl_xor(csa, 32);
    float* fb = (float*)sP;
    if (lane < 16) fb[wiE * 64 + wjE * 16 + lane] = csa;
    __syncthreads();
    float csr[2];
    #pragma unroll
    for (int tj = 0; tj < 2; ++tj) {
        const int m = wj * 32 + tj * 16 + m16;
        csr[tj] = 1.0f / (1e-9f + fb[m] + fb[64 + m]);
    }

    // d = h - xr*csr -> sD (fp16, swizzled [64 m][256 c], overlays sXV)
    const half_t* hb = h + (size_t)b * sNC;
    half_t* sD = sXV;
    #pragma unroll
    for (int ti = 0; ti < 4; ++ti) {
        const int cg = wi * 64 + ti * 16 + quad * 4;
        const int cc = (cg >> 3) ^ (m16 & 7);      // swizzled 16B chunk
        const int sub = (quad & 1) * 4;
        #pragma unroll
        for (int tj = 0; tj < 2; ++tj) {
            const int mr = wj * 32 + tj * 16 + m16;
            const int mg = j0 + mr;
            const half4 hv = *(const half4*)&hb[(size_t)mg * Cc + cg];
            half4 o;
            #pragma unroll
            for (int r = 0; r < 4; ++r)
                o[r] = (half_t)((float)hv[r] - acc[ti][tj][r] * csr[tj]);
            *(half4*)&sD[(size_t)mr * 256 + cc * 8 + sub] = o;
        }
    }
    __syncthreads();   // sD complete (fb reads also done)

    // T phase: T[co][m] = sum_c tw[co][c] * d[m][c]; tw streamed from L2
    float4v acc2[4][2];
    #pragma unroll
    for (int i = 0; i < 4; ++i)
        #pragma unroll
        for (int j = 0; j < 2; ++j) acc2[i][j] = (float4v)0.f;
    #pragma unroll
    for (int ks = 0; ks < 8; ++ks) {
        half8 af[4], bf[2];
        #pragma unroll
        for (int tm = 0; tm < 4; ++tm)
            af[tm] = *(const half8*)&sD[(size_t)(tm * 16 + m16) * 256
                                        + (((ks * 4 + quad) ^ (m16 & 7)) * 8)];
        #pragma unroll
        for (int tc = 0; tc < 2; ++tc)
            bf[tc] = *(const half8*)&tw[(size_t)(wjT * 32 + tc * 16 + m16) * 256
                                        + ks * 32 + quad * 8];
        #pragma unroll
        for (int tm = 0; tm < 4; ++tm)
            #pragma unroll
            for (int tc = 0; tc < 2; ++tc)
                acc2[tm][tc] = __builtin_amdgcn_mfma_f32_16x16x32_f16(
                    af[tm], bf[tc], acc2[tm][tc], 0, 0, 0);
    }

    // epilogue: out = h + relu(bn(T + tb)); hNext fp16
    const long yB = (long)4 * Cc * Nn;
    float* yb = outL + (size_t)b * yB;
    half_t* hn = hNext ? hNext + (size_t)b * sNC : nullptr;
    #pragma unroll
    for (int tc = 0; tc < 2; ++tc) {
        const int co = wjT * 32 + tc * 16 + m16;
        const float tb2 = tb[co];
        const float sc2 = bng[co] * rsqrtf(bnv[co] + 1e-3f);
        const float sh2 = bnb[co] - bnm[co] * sc2;
        #pragma unroll
        for (int tm = 0; tm < 4; ++tm) {
            const int mg = j0 + tm * 16 + quad * 4;
            float4v o;
            #pragma unroll
            for (int r = 0; r < 4; ++r) {
                const float t2  = acc2[tm][tc][r] + tb2;
                const float rel = fmaxf(fmaf(t2, sc2, sh2), 0.f);
                const float hv  = (float)hb[(size_t)(mg + r) * Cc + co];
                const float ov  = hv + rel;
                o[r] = ov;
                if (hn) hn[(size_t)(mg + r) * Cc + co] = (half_t)ov;
            }
            *(float4v*)&yb[(size_t)co * Nn + mg] = o;
        }
    }
}

// x [B,C,N] fp32 -> xT [B,N,C] fp16
__global__ __launch_bounds__(256)
void xpose_cast(const float* __restrict__ x, half_t* __restrict__ xT)
{
    __shared__ half_t tile[32][33];
    const int tx = threadIdx.x & 31, ty = threadIdx.x >> 5;
    const int n0 = blockIdx.x * 32, c0 = blockIdx.y * 32, b = blockIdx.z;
    #pragma unroll
    for (int r = 0; r < 4; ++r)
        tile[ty * 4 + r][tx] =
            (half_t)x[((size_t)b * Cc + c0 + ty * 4 + r) * Nn + n0 + tx];
    __syncthreads();
    #pragma unroll
    for (int r = 0; r < 4; ++r)
        xT[((size_t)b * Nn + n0 + ty * 4 + r) * Cc + c0 + tx] = tile[tx][ty * 4 + r];
}

// single kernel casting all 5 weight tensors into one fp16 arena
__global__ __launch_bounds__(256)
void castall(const float* __restrict__ c1, const float* __restrict__ c2,
             const float* __restrict__ qk, const float* __restrict__ vw,
             const float* __restrict__ tw, half_t* __restrict__ dst)
{
    const int i = (blockIdx.x * 256 + threadIdx.x) * 4;   // grid 768 -> 786432 elems
    const float* s; int o;
    if      (i < 65536)  { s = c1; o = 0; }
    else if (i < 131072) { s = c2; o = 65536; }
    else if (i < 196608) { s = qk; o = 131072; }
    else if (i < 458752) { s = vw; o = 196608; }
    else                 { s = tw; o = 458752; }
    const float4v v = *(const float4v*)(s + (i - o));
    half4 out;
    #pragma unroll
    for (int r = 0; r < 4; ++r) out[r] = (half_t)v[r];
    *(half4*)(dst + i) = out;
}

extern "C" void kernel_launch(void* const* d_in, const int* in_sizes, int n_in,
                              void* d_out, int out_size, void* d_ws, size_t ws_size,
                              hipStream_t stream)
{
    const float* x    = (const float*)d_in[0];
    const float* c1w  = (const float*)d_in[1];
    const float* c2w  = (const float*)d_in[2];
    const float* bn1g = (const float*)d_in[3], *bn1b = (const float*)d_in[4];
    const float* bn1m = (const float*)d_in[5], *bn1v = (const float*)d_in[6];
    const float* bn2g = (const float*)d_in[7], *bn2b = (const float*)d_in[8];
    const float* bn2m = (const float*)d_in[9], *bn2v = (const float*)d_in[10];
    const float* qkw  = (const float*)d_in[11];
    const float* vw   = (const float*)d_in[12];
    const float* vb   = (const float*)d_in[13];
    const float* tw   = (const float*)d_in[14];
    const float* tb   = (const float*)d_in[15];
    const float* sag  = (const float*)d_in[16];
    const float* sab  = (const float*)d_in[17];
    const float* sam  = (const float*)d_in[18];
    const float* sav  = (const float*)d_in[19];
    float* out = (float*)d_out;

    // ---- workspace layout ----
    char* ws = (char*)d_ws;
    const size_t HSZ = (size_t)Bn * Nn * Cc * 2;          // 16 MB
    half_t* xT   = (half_t*)(ws);
    half_t* hA   = (half_t*)(ws + HSZ);
    half_t* hBuf = (half_t*)(ws + 2 * HSZ);
    half_t* q_s  = (half_t*)(ws + 3 * HSZ);               // 4 MB
    half_t* xv_s = (half_t*)(ws + 3 * HSZ + (size_t)4194304);       // 16 MB
    float*  Pbuf = (float*) (ws + 4 * HSZ + (size_t)4194304);       // 4 MB
    float*  offp = (float*) (ws + 4 * HSZ + (size_t)8388608);       // 128 KB
    half_t* warena = (half_t*)(ws + 4 * HSZ + (size_t)8519680);     // 1.5 MB
    half_t* wc1  = warena;
    half_t* wc2  = wc1 + 65536;
    half_t* wqk  = wc2 + 65536;
    half_t* wv   = wqk + 65536;
    half_t* wt   = wv  + 262144;

    dim3 blk(256);

    castall<<<768, blk, 0, stream>>>(c1w, c2w, qkw, vw, tw, warena);
    xpose_cast<<<dim3(Nn / 32, Cc / 32, Bn), blk, 0, stream>>>(x, xT);

    mgemm<EPI_H, 256, 128, 4, 2, false><<<dim3(16, 1, Bn), dim3(512), 0, stream>>>(
        wc1, 0, xT, sNC, hA, sNC, Cc,
        nullptr, bn1g, bn1b, bn1m, bn1v, Cc, nullptr, nullptr);
    mgemm<EPI_H, 256, 128, 4, 2, false><<<dim3(16, 1, Bn), dim3(512), 0, stream>>>(
        wc2, 0, hA, sNC, hBuf, sNC, Cc,
        nullptr, bn2g, bn2b, bn2m, bn2v, Cc, nullptr, nullptr);

    half_t* hcur = hBuf;
    half_t* hnxt = hA;
    for (int L = 0; L < 4; ++L) {
        mgemm<EPI_RAW, 64, 256, 1, 4, false><<<dim3(8, 1, Bn), blk, 0, stream>>>(
            wqk + (long)L * C4 * Cc, 0, hcur, sNC, q_s, sNQ, C4,
            nullptr, nullptr, nullptr, nullptr, nullptr, Cc, nullptr, nullptr);
        // softmax stats (parallel, XCD-clustered 1-D grid)
        estats<<<dim3(4096), blk, 0, stream>>>(q_s, Pbuf);
        // xv[c][n] fp16 + folded statsreduce (Pbuf -> offp, hidden in prologue)
        mgemm<EPI_XV, 128, 256, 2, 4, true><<<dim3(1, 16, Bn), dim3(512), 0, stream>>>(
            hcur, sNC, wv + (long)L * Cc * Cc, 0, xv_s, (long)Cc * Nn, Nn,
            vb + L * Cc, nullptr, nullptr, nullptr, nullptr, Cc, Pbuf, offp);
        flashxr<<<dim3(512), dim3(512), 0, stream>>>(
            q_s, xv_s, hcur, offp,
            wt + (long)L * Cc * Cc, tb + L * Cc,
            sag + L * Cc, sab + L * Cc, sam + L * Cc, sav + L * Cc,
            out + (long)L * Cc * Nn, (L < 3) ? hnxt : nullptr);
        half_t* tmp = hcur; hcur = hnxt; hnxt = tmp;
    }
}

// Round 14
// 671.517 us; speedup vs baseline: 1.5332x; 1.0087x over previous
//
#include <hip/hip_runtime.h>
#include <hip/hip_bf16.h>
#include <hip/hip_fp16.h>

// Problem constants: B=16, C=256, N=2048, NUM_SA=4
static constexpr int Bn = 16;
static constexpr int Cc = 256;
static constexpr int Nn = 2048;
static constexpr int C4 = 64;
static constexpr float LOG2E = 1.4426950408889634f;

typedef _Float16 half_t;
typedef __attribute__((ext_vector_type(8))) _Float16 half8;
typedef __attribute__((ext_vector_type(4))) _Float16 half4;
typedef __attribute__((ext_vector_type(8))) short short8;
typedef __attribute__((ext_vector_type(4))) float float4v;

static constexpr long sNC = (long)Nn * Cc;   // 524288
static constexpr long sNQ = (long)Nn * C4;   // 131072

#define DEVI __device__ __forceinline__

DEVI float bf2f(unsigned short u) { return __uint_as_float(((unsigned)u) << 16); }
DEVI unsigned short f2bf(float f) {
    unsigned x = __float_as_uint(f);
    x += 0x7fffu + ((x >> 16) & 1u);   // RNE
    return (unsigned short)(x >> 16);
}

// async global->LDS, 16B per lane. LDS dest = wave-uniform base + lane*16.
DEVI void gload16(const void* g, void* l) {
    __builtin_amdgcn_global_load_lds(
        (const __attribute__((address_space(1))) unsigned int*)g,
        (__attribute__((address_space(3))) unsigned int*)l, 16, 0, 0);
}

enum { EPI_RAW = 0, EPI_H = 1, EPI_XV = 2 };

// Canonical MFMA GEMM: Y[j][i] = epi( sum_k A[i*K+k] * B[j*K+k] )
// EPI_XV additionally folds the statsreduce (Pbuf 16-partial merge -> offp),
// hidden under the first stage drain.
template<int MODE, int BM, int BN, int WI, int WJ, bool BF16OUT>
__global__ __launch_bounds__(WI * WJ * 64)
void mgemm(const half_t* __restrict__ A, long aB,
           const half_t* __restrict__ Bm, long bB,
           void* __restrict__ Yv, long yB, int ldy,
           const float* __restrict__ bias,
           const float* __restrict__ bng, const float* __restrict__ bnb,
           const float* __restrict__ bnm, const float* __restrict__ bnv,
           int K,
           const float* __restrict__ Pbuf, float* __restrict__ offp)
{
    constexpr int NW = WI * WJ;
    __shared__ __align__(16) half_t Als[2][BM][32];
    __shared__ __align__(16) half_t Bls[2][BN][32];

    const int tid  = threadIdx.x;
    const int w    = tid >> 6;
    const int lane = tid & 63;
    const int wi   = w % WI;
    const int wj   = w / WI;
    const int quad = lane >> 4, m16 = lane & 15;
    const int lr   = lane >> 2, lc = lane & 3;
    const int b    = blockIdx.z;
    const int j0   = blockIdx.x * BN;
    const int i0   = blockIdx.y * BM;

    const half_t* Ab = A + (size_t)b * aB;
    const half_t* Bb = Bm + (size_t)b * bB;

    float4v acc[4][4];
    #pragma unroll
    for (int i = 0; i < 4; ++i)
        #pragma unroll
        for (int j = 0; j < 4; ++j) acc[i][j] = (float4v)0.f;

    bool first = true;
    for (int k0 = 0; k0 < K; k0 += 64) {
        #pragma unroll
        for (int s = 0; s < 2; ++s) {
            const int kk = k0 + s * 32 + lc * 8;
            #pragma unroll
            for (int t = 0; t < BM / (16 * NW); ++t) {
                const int row = (t * NW + w) * 16;
                gload16(Ab + (size_t)(i0 + row + lr) * K + kk, &Als[s][row][0]);
            }
            #pragma unroll
            for (int t = 0; t < BN / (16 * NW); ++t) {
                const int row = (t * NW + w) * 16;
                gload16(Bb + (size_t)(j0 + row + lr) * K + kk, &Bls[s][row][0]);
            }
        }
        if (MODE == EPI_XV && first && Pbuf && tid < 128) {
            const int m = blockIdx.y * 128 + tid;
            const float2* p = (const float2*)(Pbuf + ((size_t)b * Nn + m) * 32);
            float M = -1e30f;
            #pragma unroll
            for (int i = 0; i < 16; ++i) M = fmaxf(M, p[i].x);
            float S = 0.f;
            #pragma unroll
            for (int i = 0; i < 16; ++i) S += p[i].y * __expf(p[i].x - M);
            offp[(size_t)b * Nn + m] = fmaf(M, LOG2E, __log2f(S));
        }
        first = false;
        __syncthreads();
        #pragma unroll
        for (int s = 0; s < 2; ++s) {
            half8 af[4], bf[4];
            #pragma unroll
            for (int t = 0; t < 4; ++t)
                af[t] = *(const half8*)&Als[s][wi * 64 + t * 16 + m16][quad * 8];
            #pragma unroll
            for (int t = 0; t < 4; ++t)
                bf[t] = *(const half8*)&Bls[s][wj * 64 + t * 16 + m16][quad * 8];
            #pragma unroll
            for (int ti = 0; ti < 4; ++ti)
                #pragma unroll
                for (int tj = 0; tj < 4; ++tj)
                    acc[ti][tj] = __builtin_amdgcn_mfma_f32_16x16x32_f16(
                        af[ti], bf[tj], acc[ti][tj], 0, 0, 0);
        }
        __syncthreads();
    }

    #pragma unroll
    for (int ti = 0; ti < 4; ++ti) {
        const int il = i0 + wi * 64 + ti * 16 + quad * 4;
        #pragma unroll
        for (int tj = 0; tj < 4; ++tj) {
            const int jl = j0 + wj * 64 + tj * 16 + m16;
            float4v v = acc[ti][tj];
            if (MODE == EPI_RAW) {
                half4 o;
                #pragma unroll
                for (int r = 0; r < 4; ++r) o[r] = (half_t)v[r];
                *(half4*)((half_t*)Yv + (size_t)b * yB + (size_t)jl * ldy + il) = o;
            } else if (MODE == EPI_H) {
                half4 o;
                #pragma unroll
                for (int r = 0; r < 4; ++r) {
                    const float sc = bng[il + r] * rsqrtf(bnv[il + r] + 1e-3f);
                    const float sh = bnb[il + r] - bnm[il + r] * sc;
                    o[r] = (half_t)fmaxf(fmaf(v[r], sc, sh), 0.f);
                }
                *(half4*)((half_t*)Yv + (size_t)b * yB + (size_t)jl * ldy + il) = o;
            } else {   // EPI_XV
                const float bj = bias[jl];
                if (BF16OUT) {
                    ushort4 o;
                    o.x = f2bf(v[0] + bj); o.y = f2bf(v[1] + bj);
                    o.z = f2bf(v[2] + bj); o.w = f2bf(v[3] + bj);
                    *(ushort4*)((unsigned short*)Yv + (size_t)b * yB + (size_t)jl * ldy + il) = o;
                } else {
                    half4 o;
                    #pragma unroll
                    for (int r = 0; r < 4; ++r) o[r] = (half_t)(v[r] + bj);
                    *(half4*)((half_t*)Yv + (size_t)b * yB + (size_t)jl * ldy + il) = o;
                }
            }
        }
    }
}

// Pass 1: E = q q^T tile stats -> Pbuf[b][m][16 iblk][2]. XCD-clustered:
// 1-D grid 4096, XCD r owns batches {2r, 2r+1} (q working set 8 MB -> L2).
__global__ __launch_bounds__(256)
void estats(const half_t* __restrict__ q, float* __restrict__ Pbuf)
{
    __shared__ __align__(16) half_t sA[128 * 64];
    __shared__ __align__(16) half_t sB[128 * 64];
    __shared__ float red[2][2][4][16][2];
    const int tid = threadIdx.x, w = tid >> 6, lane = tid & 63;
    const int wi = w & 1, wj = w >> 1, quad = lane >> 4, m16 = lane & 15;
    const int f = blockIdx.x;
    const int W = (f & 7) * 512 + (f >> 3);     // bijective over [0,4096)
    const int b = W >> 8;
    const int rem = W & 255;
    const int j0 = (rem & 15) * 128;
    const int ib = rem >> 4;
    const int i0 = ib * 128;
    const half_t* qb = q + (size_t)b * sNQ;

    #pragma unroll
    for (int t = 0; t < 4; ++t) {
        const int g = w * 256 + t * 64 + lane;
        const int r = g >> 3, c = g & 7;
        const int cs = c ^ (r & 7);
        gload16(qb + (size_t)(i0 + r) * 64 + cs * 8, sA + (w * 256 + t * 64) * 8);
        gload16(qb + (size_t)(j0 + r) * 64 + cs * 8, sB + (w * 256 + t * 64) * 8);
    }
    __syncthreads();

    half8 an[4][2], bm[4][2];
    #pragma unroll
    for (int t = 0; t < 4; ++t)
        #pragma unroll
        for (int ks = 0; ks < 2; ++ks) {
            const int pc = ((ks * 4 + quad) ^ (m16 & 7)) * 8;
            an[t][ks] = *(const half8*)&sA[(wi * 64 + t * 16 + m16) * 64 + pc];
            bm[t][ks] = *(const half8*)&sB[(wj * 64 + t * 16 + m16) * 64 + pc];
        }

    #pragma unroll
    for (int tj = 0; tj < 4; ++tj) {
        float4v e[4];
        #pragma unroll
        for (int ti = 0; ti < 4; ++ti) {
            e[ti] = (float4v)0.f;
            e[ti] = __builtin_amdgcn_mfma_f32_16x16x32_f16(an[ti][0], bm[tj][0], e[ti], 0, 0, 0);
            e[ti] = __builtin_amdgcn_mfma_f32_16x16x32_f16(an[ti][1], bm[tj][1], e[ti], 0, 0, 0);
        }
        float lmax = -1e30f;
        #pragma unroll
        for (int ti = 0; ti < 4; ++ti)
            #pragma unroll
            for (int r = 0; r < 4; ++r) lmax = fmaxf(lmax, e[ti][r]);
        lmax = fmaxf(lmax, __shfl_xor(lmax, 16));
        lmax = fmaxf(lmax, __shfl_xor(lmax, 32));
        float ls = 0.f;
        #pragma unroll
        for (int ti = 0; ti < 4; ++ti)
            #pragma unroll
            for (int r = 0; r < 4; ++r) ls += __expf(e[ti][r] - lmax);
        ls += __shfl_xor(ls, 16);
        ls += __shfl_xor(ls, 32);
        if (quad == 0) { red[wi][wj][tj][m16][0] = lmax; red[wi][wj][tj][m16][1] = ls; }
    }
    __syncthreads();
    if (tid < 128) {
        const int wj2 = tid >> 6, tj2 = (tid >> 4) & 3, mm = tid & 15;
        const float m0 = red[0][wj2][tj2][mm][0], s0 = red[0][wj2][tj2][mm][1];
        const float m1 = red[1][wj2][tj2][mm][0], s1 = red[1][wj2][tj2][mm][1];
        const float M = fmaxf(m0, m1);
        const float S = s0 * __expf(m0 - M) + s1 * __expf(m1 - M);
        const int m = j0 + wj2 * 64 + tj2 * 16 + mm;
        *(float2*)(Pbuf + (((size_t)b * Nn + m) * 16 + ib) * 2) = make_float2(M, S);
    }
}

// Pass 2: fused attention-apply + t-GEMM + epilogue + NEXT-LAYER q-GEMM.
// Round-13 body (85 us). New QN phase (qn != nullptr): the epilogue also
// spills hNext into sH (sXV reuse; sD dead after T phase), then each wave
// runs 16 MFMA computing q_next[m][o] = sum_c hN[m][c]*qk_next[o][c] with
// qk weights streamed from L2 (like tw). q double-buffered at the launcher
// (in-place write would race with blocks still streaming all q rows).
__global__ __launch_bounds__(512)
void flashxr(const half_t* __restrict__ q, const half_t* __restrict__ xv,
             const half_t* __restrict__ h, const float* __restrict__ offp,
             const half_t* __restrict__ tw, const float* __restrict__ tb,
             const float* __restrict__ bng, const float* __restrict__ bnb,
             const float* __restrict__ bnm, const float* __restrict__ bnv,
             float* __restrict__ outL, half_t* __restrict__ hNext,
             const half_t* __restrict__ qkn, half_t* __restrict__ qn)
{
    __shared__ __align__(16) half_t sXV[256 * 64];    // 32 KB; sD / sH reuse
    __shared__ __align__(16) half_t sQA[2][64 * 64];  // 16 KB, next-chunk dbuf
    __shared__ __align__(16) half_t sP[64 * 64];      // 8 KB: P tile / cs buf
    __shared__ float sOff[Nn];                        // 8 KB

    const int tid = threadIdx.x, w = tid >> 6, lane = tid & 63;
    const int quad = lane >> 4, m16 = lane & 15;
    const int wiE = w & 1, wjE = w >> 1;        // E: n-32-half, m-16-tile (4)
    const int wi = w & 3, wj = w >> 2;          // XR: c-64-tile (4), m-32-tile (2)
    const int wjT = w;                          // T: co-32-tile (8)
    const int f = blockIdx.x;
    const int W = (f & 7) * 64 + (f >> 3);      // bijective over [0,512)
    const int b = W >> 5, j0 = (W & 31) * 64;
    const half_t* qb  = q + (size_t)b * sNQ;
    const half_t* xvb = xv + (size_t)b * sNC;   // [256][2048] half bits

    const int sr = tid >> 3, sc = tid & 7;      // 64-row staging coords (sQA)
    const int qsw = (sc ^ (sr & 7)) * 8;

    // ---- prologue: stage sQA[0] + sOff (8 KB = 512 x 16B); bq regs ----
    gload16(qb + (size_t)sr * 64 + qsw, &sQA[0][(size_t)tid * 8]);
    gload16(offp + (size_t)b * Nn + (size_t)tid * 4, sOff + (size_t)tid * 4);

    half8 bq[2];
    #pragma unroll
    for (int s = 0; s < 2; ++s)
        bq[s] = *(const half8*)(qb + (size_t)(j0 + wjE * 16 + m16) * 64 + (s * 4 + quad) * 8);

    __syncthreads();   // drains sQA[0] + sOff stages

    float4v acc[4][2];
    #pragma unroll
    for (int i = 0; i < 4; ++i)
        #pragma unroll
        for (int j = 0; j < 2; ++j) acc[i][j] = (float4v)0.f;
    float csa = 0.f;
    const int mrow = wjE * 16 + m16;

    for (int nc = 0; nc < 32; ++nc) {
        // stage sXV for THIS chunk; stage NEXT chunk's q into other sQA buf
        #pragma unroll
        for (int t = 0; t < 4; ++t) {
            const int g = t * 512 + tid;
            const int r = g >> 3, c = g & 7;
            gload16(xvb + (size_t)r * Nn + nc * 64 + ((c ^ (r & 7)) * 8),
                    sXV + (size_t)g * 8);
        }
        if (nc < 31)
            gload16(qb + (size_t)((nc + 1) * 64 + sr) * 64 + qsw,
                    &sQA[(nc + 1) & 1][(size_t)tid * 8]);
        __syncthreads();   // drains own stages; sibling block overlaps stall

        // E phase from sQA[nc&1] (staged previous chunk)
        const half_t* qA = &sQA[nc & 1][0];
        const int nbase = nc * 64 + wiE * 32 + quad * 4;
        #pragma unroll
        for (int ti = 0; ti < 2; ++ti) {
            const int nl = wiE * 32 + ti * 16 + m16;
            const half8 an0 = *(const half8*)&qA[(size_t)nl * 64 + ((quad ^ (m16 & 7)) * 8)];
            const half8 an1 = *(const half8*)&qA[(size_t)nl * 64 + (((4 + quad) ^ (m16 & 7)) * 8)];
            float4v e = (float4v)0.f;
            e = __builtin_amdgcn_mfma_f32_16x16x32_f16(an0, bq[0], e, 0, 0, 0);
            e = __builtin_amdgcn_mfma_f32_16x16x32_f16(an1, bq[1], e, 0, 0, 0);
            const float4v o4 = *(const float4v*)&sOff[nbase + ti * 16];
            float c0 = 0.f; ushort4 pk;
            #pragma unroll
            for (int r = 0; r < 4; ++r) {
                const float p = __builtin_amdgcn_exp2f(fmaf(e[r], LOG2E, -o4[r]));
                c0 += p; (&pk.x)[r] = f2bf(p);
            }
            csa += c0;
            const int pc = (wiE * 4 + ti * 2 + (quad >> 1)) ^ (m16 & 7);
            *(ushort4*)&((unsigned short*)sP)[(size_t)mrow * 64 + pc * 8 + (quad & 1) * 4] = pk;
        }
        __syncthreads();   // publishes sP

        // XR phase: acc[c][m] += xv[c][k=n] * P[m][k=n], K = 64
        #pragma unroll
        for (int ks = 0; ks < 2; ++ks) {
            short8 xa[4], pb[2];
            #pragma unroll
            for (int ti = 0; ti < 4; ++ti)
                xa[ti] = *(const short8*)&sXV[(size_t)(wi * 64 + ti * 16 + m16) * 64
                                              + (((ks * 4 + quad) ^ (m16 & 7)) * 8)];
            #pragma unroll
            for (int tj = 0; tj < 2; ++tj)
                pb[tj] = *(const short8*)&sP[(size_t)(wj * 32 + tj * 16 + m16) * 64
                                             + (((ks * 4 + quad) ^ (m16 & 7)) * 8)];
            __builtin_amdgcn_s_setprio(1);
            #pragma unroll
            for (int ti = 0; ti < 4; ++ti)
                #pragma unroll
                for (int tj = 0; tj < 2; ++tj)
                    acc[ti][tj] = __builtin_amdgcn_mfma_f32_16x16x32_bf16(
                        xa[ti], pb[tj], acc[ti][tj], 0, 0, 0);
            __builtin_amdgcn_s_setprio(0);
        }
        __syncthreads();   // XR reads done before next chunk overwrites
    }

    // colsum reduce: quad butterfly, then cross-wiE via LDS (sP as floats)
    csa += __shfl_xor(csa, 16);
    csa += __shfl_xor(csa, 32);
    float* fb = (float*)sP;
    if (lane < 16) fb[wiE * 64 + wjE * 16 + lane] = csa;
    __syncthreads();
    float csr[2];
    #pragma unroll
    for (int tj = 0; tj < 2; ++tj) {
        const int m = wj * 32 + tj * 16 + m16;
        csr[tj] = 1.0f / (1e-9f + fb[m] + fb[64 + m]);
    }

    // d = h - xr*csr -> sD (fp16, swizzled [64 m][256 c], overlays sXV)
    const half_t* hb = h + (size_t)b * sNC;
    half_t* sD = sXV;
    #pragma unroll
    for (int ti = 0; ti < 4; ++ti) {
        const int cg = wi * 64 + ti * 16 + quad * 4;
        const int cc = (cg >> 3) ^ (m16 & 7);      // swizzled 16B chunk
        const int sub = (quad & 1) * 4;
        #pragma unroll
        for (int tj = 0; tj < 2; ++tj) {
            const int mr = wj * 32 + tj * 16 + m16;
            const int mg = j0 + mr;
            const half4 hv = *(const half4*)&hb[(size_t)mg * Cc + cg];
            half4 o;
            #pragma unroll
            for (int r = 0; r < 4; ++r)
                o[r] = (half_t)((float)hv[r] - acc[ti][tj][r] * csr[tj]);
            *(half4*)&sD[(size_t)mr * 256 + cc * 8 + sub] = o;
        }
    }
    __syncthreads();   // sD complete (fb reads also done)

    // T phase: T[co][m] = sum_c tw[co][c] * d[m][c]; tw streamed from L2
    float4v acc2[4][2];
    #pragma unroll
    for (int i = 0; i < 4; ++i)
        #pragma unroll
        for (int j = 0; j < 2; ++j) acc2[i][j] = (float4v)0.f;
    #pragma unroll
    for (int ks = 0; ks < 8; ++ks) {
        half8 af[4], bf[2];
        #pragma unroll
        for (int tm = 0; tm < 4; ++tm)
            af[tm] = *(const half8*)&sD[(size_t)(tm * 16 + m16) * 256
                                        + (((ks * 4 + quad) ^ (m16 & 7)) * 8)];
        #pragma unroll
        for (int tc = 0; tc < 2; ++tc)
            bf[tc] = *(const half8*)&tw[(size_t)(wjT * 32 + tc * 16 + m16) * 256
                                        + ks * 32 + quad * 8];
        #pragma unroll
        for (int tm = 0; tm < 4; ++tm)
            #pragma unroll
            for (int tc = 0; tc < 2; ++tc)
                acc2[tm][tc] = __builtin_amdgcn_mfma_f32_16x16x32_f16(
                    af[tm], bf[tc], acc2[tm][tc], 0, 0, 0);
    }

    if (qn) __syncthreads();   // all T-phase sD reads done before sH overwrite

    // epilogue: out = h + relu(bn(T + tb)); hNext fp16; optional sH spill
    half_t* sH = sXV;
    const long yB = (long)4 * Cc * Nn;
    float* yb = outL + (size_t)b * yB;
    half_t* hn = hNext ? hNext + (size_t)b * sNC : nullptr;
    #pragma unroll
    for (int tc = 0; tc < 2; ++tc) {
        const int co = wjT * 32 + tc * 16 + m16;
        const float tb2 = tb[co];
        const float sc2 = bng[co] * rsqrtf(bnv[co] + 1e-3f);
        const float sh2 = bnb[co] - bnm[co] * sc2;
        #pragma unroll
        for (int tm = 0; tm < 4; ++tm) {
            const int mg = j0 + tm * 16 + quad * 4;
            float4v o;
            #pragma unroll
            for (int r = 0; r < 4; ++r) {
                const float t2  = acc2[tm][tc][r] + tb2;
                const float rel = fmaxf(fmaf(t2, sc2, sh2), 0.f);
                const float hv  = (float)hb[(size_t)(mg + r) * Cc + co];
                const float ov  = hv + rel;
                o[r] = ov;
                if (hn) hn[(size_t)(mg + r) * Cc + co] = (half_t)ov;
                if (qn) {
                    const int row = tm * 16 + quad * 4 + r;            // local m
                    const int chk = ((co >> 3) ^ (row & 7));           // swizzle
                    sH[(size_t)row * 256 + chk * 8 + (co & 7)] = (half_t)ov;
                }
            }
            *(float4v*)&yb[(size_t)co * Nn + mg] = o;
        }
    }

    if (qn) {
        __syncthreads();   // sH complete
        // QN phase: q_next[m][o] = sum_c hN[m][c] * qkn[o][c], K=256.
        // Wave w: o-tile = w&3, m-tiles = (w>>2)*2 + {0,1}; 16 MFMA/wave.
        const int ot = w & 3;
        const int mt0 = (w >> 2) * 2;
        float4v acc3[2];
        acc3[0] = (float4v)0.f; acc3[1] = (float4v)0.f;
        #pragma unroll
        for (int ks = 0; ks < 8; ++ks) {
            const half8 bf = *(const half8*)&qkn[(size_t)(ot * 16 + m16) * 256
                                                + ks * 32 + quad * 8];
            #pragma unroll
            for (int mi = 0; mi < 2; ++mi) {
                const half8 af = *(const half8*)&sH[(size_t)((mt0 + mi) * 16 + m16) * 256
                                                    + (((ks * 4 + quad) ^ (m16 & 7)) * 8)];
                acc3[mi] = __builtin_amdgcn_mfma_f32_16x16x32_f16(af, bf, acc3[mi], 0, 0, 0);
            }
        }
        half_t* qnb = qn + (size_t)b * sNQ;
        #pragma unroll
        for (int mi = 0; mi < 2; ++mi)
            #pragma unroll
            for (int r = 0; r < 4; ++r)
                qnb[(size_t)(j0 + (mt0 + mi) * 16 + quad * 4 + r) * 64
                    + ot * 16 + m16] = (half_t)acc3[mi][r];
    }
}

// x [B,C,N] fp32 -> xT [B,N,C] fp16
__global__ __launch_bounds__(256)
void xpose_cast(const float* __restrict__ x, half_t* __restrict__ xT)
{
    __shared__ half_t tile[32][33];
    const int tx = threadIdx.x & 31, ty = threadIdx.x >> 5;
    const int n0 = blockIdx.x * 32, c0 = blockIdx.y * 32, b = blockIdx.z;
    #pragma unroll
    for (int r = 0; r < 4; ++r)
        tile[ty * 4 + r][tx] =
            (half_t)x[((size_t)b * Cc + c0 + ty * 4 + r) * Nn + n0 + tx];
    __syncthreads();
    #pragma unroll
    for (int r = 0; r < 4; ++r)
        xT[((size_t)b * Nn + n0 + ty * 4 + r) * Cc + c0 + tx] = tile[tx][ty * 4 + r];
}

// single kernel casting all 5 weight tensors into one fp16 arena
__global__ __launch_bounds__(256)
void castall(const float* __restrict__ c1, const float* __restrict__ c2,
             const float* __restrict__ qk, const float* __restrict__ vw,
             const float* __restrict__ tw, half_t* __restrict__ dst)
{
    const int i = (blockIdx.x * 256 + threadIdx.x) * 4;   // grid 768 -> 786432 elems
    const float* s; int o;
    if      (i < 65536)  { s = c1; o = 0; }
    else if (i < 131072) { s = c2; o = 65536; }
    else if (i < 196608) { s = qk; o = 131072; }
    else if (i < 458752) { s = vw; o = 196608; }
    else                 { s = tw; o = 458752; }
    const float4v v = *(const float4v*)(s + (i - o));
    half4 out;
    #pragma unroll
    for (int r = 0; r < 4; ++r) out[r] = (half_t)v[r];
    *(half4*)(dst + i) = out;
}

extern "C" void kernel_launch(void* const* d_in, const int* in_sizes, int n_in,
                              void* d_out, int out_size, void* d_ws, size_t ws_size,
                              hipStream_t stream)
{
    const float* x    = (const float*)d_in[0];
    const float* c1w  = (const float*)d_in[1];
    const float* c2w  = (const float*)d_in[2];
    const float* bn1g = (const float*)d_in[3], *bn1b = (const float*)d_in[4];
    const float* bn1m = (const float*)d_in[5], *bn1v = (const float*)d_in[6];
    const float* bn2g = (const float*)d_in[7], *bn2b = (const float*)d_in[8];
    const float* bn2m = (const float*)d_in[9], *bn2v = (const float*)d_in[10];
    const float* qkw  = (const float*)d_in[11];
    const float* vw   = (const float*)d_in[12];
    const float* vb   = (const float*)d_in[13];
    const float* tw   = (const float*)d_in[14];
    const float* tb   = (const float*)d_in[15];
    const float* sag  = (const float*)d_in[16];
    const float* sab  = (const float*)d_in[17];
    const float* sam  = (const float*)d_in[18];
    const float* sav  = (const float*)d_in[19];
    float* out = (float*)d_out;

    // ---- workspace layout ----
    char* ws = (char*)d_ws;
    const size_t HSZ = (size_t)Bn * Nn * Cc * 2;          // 16 MB
    half_t* xT   = (half_t*)(ws);
    half_t* hA   = (half_t*)(ws + HSZ);
    half_t* hBuf = (half_t*)(ws + 2 * HSZ);
    half_t* q_sA = (half_t*)(ws + 3 * HSZ);               // 4 MB
    half_t* xv_s = (half_t*)(ws + 3 * HSZ + (size_t)4194304);       // 16 MB
    float*  Pbuf = (float*) (ws + 4 * HSZ + (size_t)4194304);       // 4 MB
    float*  offp = (float*) (ws + 4 * HSZ + (size_t)8388608);       // 128 KB
    half_t* warena = (half_t*)(ws + 4 * HSZ + (size_t)8519680);     // 1.5 MB
    half_t* q_sB = (half_t*)(ws + 4 * HSZ + (size_t)8519680 + (size_t)2097152);  // 4 MB
    half_t* wc1  = warena;
    half_t* wc2  = wc1 + 65536;
    half_t* wqk  = wc2 + 65536;
    half_t* wv   = wqk + 65536;
    half_t* wt   = wv  + 262144;

    dim3 blk(256);

    castall<<<768, blk, 0, stream>>>(c1w, c2w, qkw, vw, tw, warena);
    xpose_cast<<<dim3(Nn / 32, Cc / 32, Bn), blk, 0, stream>>>(x, xT);

    mgemm<EPI_H, 256, 128, 4, 2, false><<<dim3(16, 1, Bn), dim3(512), 0, stream>>>(
        wc1, 0, xT, sNC, hA, sNC, Cc,
        nullptr, bn1g, bn1b, bn1m, bn1v, Cc, nullptr, nullptr);
    mgemm<EPI_H, 256, 128, 4, 2, false><<<dim3(16, 1, Bn), dim3(512), 0, stream>>>(
        wc2, 0, hA, sNC, hBuf, sNC, Cc,
        nullptr, bn2g, bn2b, bn2m, bn2v, Cc, nullptr, nullptr);

    // q for layer 0 only; layers 1-3 get q from flashxr's fused QN phase
    mgemm<EPI_RAW, 64, 256, 1, 4, false><<<dim3(8, 1, Bn), blk, 0, stream>>>(
        wqk, 0, hBuf, sNC, q_sA, sNQ, C4,
        nullptr, nullptr, nullptr, nullptr, nullptr, Cc, nullptr, nullptr);

    half_t* hcur = hBuf;
    half_t* hnxt = hA;
    half_t* qcur = q_sA;
    half_t* qnxt = q_sB;
    for (int L = 0; L < 4; ++L) {
        // softmax stats (parallel, XCD-clustered 1-D grid)
        estats<<<dim3(4096), blk, 0, stream>>>(qcur, Pbuf);
        // xv[c][n] fp16 + folded statsreduce (Pbuf -> offp, hidden in prologue)
        mgemm<EPI_XV, 128, 256, 2, 4, true><<<dim3(1, 16, Bn), dim3(512), 0, stream>>>(
            hcur, sNC, wv + (long)L * Cc * Cc, 0, xv_s, (long)Cc * Nn, Nn,
            vb + L * Cc, nullptr, nullptr, nullptr, nullptr, Cc, Pbuf, offp);
        // fused attn + t-GEMM + epilogue + next-layer q (L<3)
        flashxr<<<dim3(512), dim3(512), 0, stream>>>(
            qcur, xv_s, hcur, offp,
            wt + (long)L * Cc * Cc, tb + L * Cc,
            sag + L * Cc, sab + L * Cc, sam + L * Cc, sav + L * Cc,
            out + (long)L * Cc * Nn, (L < 3) ? hnxt : nullptr,
            wqk + (long)(L + 1 < 4 ? L + 1 : 0) * C4 * Cc,
            (L < 3) ? qnxt : nullptr);
        half_t* tmp = hcur; hcur = hnxt; hnxt = tmp;
        half_t* tq  = qcur; qcur = qnxt; qnxt = tq;
    }
}